// Round 5
// baseline (600.624 us; speedup 1.0000x reference)
//
#include <hip/hip_runtime.h>

typedef unsigned int uint;
typedef unsigned short ushort;
typedef __attribute__((ext_vector_type(8))) short short8v;
typedef __attribute__((ext_vector_type(4))) float f32x4;

#define D 128
#define BMG 32       // gather tile rows
#define LDH 136      // LDS row stride in ushorts (272 B, b128-aligned, conflict-free)
#define NPB 64       // nodes per coarse bucket
#define PSHIFT 26    // pairs pack: local_dst(6b) << 26 | src(26b)  (needs N < 2^26)

// ---------- edge-index dtype hedge (int64 vs int32), wave-uniform ----------
__device__ __forceinline__ bool ei_is64(const int* ei32) {
    return ((ei32[1] | ei32[3] | ei32[5] | ei32[7]) == 0);
}
__device__ __forceinline__ float b2f(ushort u) { return __uint_as_float((uint)u << 16); }
__device__ __forceinline__ ushort f2b(float f) {   // RNE
    uint a = __float_as_uint(f);
    return (ushort)((a + 0x7fffu + ((a >> 16) & 1u)) >> 16);
}

// ---- prep: coarse dst-histogram + x -> bf16 + W1/W2 -> bf16 transpose ----
__global__ __launch_bounds__(256) void gin_prep(
    const void* __restrict__ ei_raw, int* __restrict__ ccnt, int nhb, int E,
    const float4* __restrict__ x4, ushort4* __restrict__ xb4, int n4, int nxb,
    const float* __restrict__ W1, const float* __restrict__ W2,
    ushort* __restrict__ w1t, ushort* __restrict__ w2t)
{
    int bid = blockIdx.x;
    if (bid < nhb) {
        int e = bid * 256 + threadIdx.x;
        if (e < E) {
            const int* ei32 = (const int*)ei_raw;
            const long long* ei64 = (const long long*)ei_raw;
            int dst = ei_is64(ei32) ? (int)ei64[e] : ei32[e];
            atomicAdd(&ccnt[dst >> 6], 1);
        }
    } else if (bid < nhb + nxb) {
        int i = (bid - nhb) * 256 + threadIdx.x;
        if (i < n4) {
            float4 v = x4[i];
            ushort4 o;
            o.x = f2b(v.x); o.y = f2b(v.y); o.z = f2b(v.z); o.w = f2b(v.w);
            xb4[i] = o;
        }
    } else {
        int idx = (bid - nhb - nxb) * 256 + threadIdx.x;   // [0, 2*128*128)
        int which = idx >> 14;
        int rem   = idx & 16383;                           // n*128 + k
        int k = rem & 127, n = rem >> 7;
        const float* W = which ? W2 : W1;
        ushort* WT = which ? w2t : w1t;
        WT[rem] = f2b(W[k * D + n]);                       // WT[n][k] = W[k][n]
    }
}

// ---- exclusive scan of coarse counts (one block, up to 4096) ----
__global__ __launch_bounds__(1024) void gin_cscan(const int* __restrict__ ccnt,
                                                  int* __restrict__ coff, int nc) {
    __shared__ int ts[1024];
    int tid = threadIdx.x;
    int base = tid * 4;
    int v[4]; int s = 0;
    #pragma unroll
    for (int j = 0; j < 4; ++j) { int idx = base + j; v[j] = (idx < nc) ? ccnt[idx] : 0; s += v[j]; }
    ts[tid] = s;
    __syncthreads();
    for (int d = 1; d < 1024; d <<= 1) {
        int t = (tid >= d) ? ts[tid - d] : 0;
        __syncthreads();
        ts[tid] += t;
        __syncthreads();
    }
    int run = ts[tid] - s;
    #pragma unroll
    for (int j = 0; j < 4; ++j) { int idx = base + j; if (idx <= nc) coff[idx] = run; run += v[j]; }
}

// ---- coarse scatter: packed (ldst,src) pairs into per-bucket regions ----
__global__ __launch_bounds__(256) void gin_cscatter(
    const void* __restrict__ ei_raw, const int* __restrict__ coff,
    int* __restrict__ ccur, uint* __restrict__ pairs, int E)
{
    int e = blockIdx.x * 256 + threadIdx.x;
    if (e >= E) return;
    const int* ei32 = (const int*)ei_raw;
    const long long* ei64 = (const long long*)ei_raw;
    int dst, src;
    if (ei_is64(ei32)) { dst = (int)ei64[e]; src = (int)ei64[E + e]; }
    else               { dst = ei32[e];      src = ei32[E + e]; }
    int c = dst >> 6;
    int p = atomicAdd(&ccur[c], 1);
    pairs[coff[c] + p] = ((uint)(dst & (NPB - 1)) << PSHIFT) | (uint)src;
}

// ---- fine sort within each coarse bucket (one block per bucket) ----
// Produces bucket[] (src grouped by node), cnt[node], off[node] (absolute).
__global__ __launch_bounds__(256) void gin_fine(
    const uint* __restrict__ pairs, const int* __restrict__ coff,
    int* __restrict__ cnt, int* __restrict__ off, int* __restrict__ bucket, int N)
{
    __shared__ int h[NPB], ex[NPB], cur[NPB];
    const int c = blockIdx.x;
    const int nb = c << 6;
    const int s = coff[c], e = coff[c + 1];
    const int tid = threadIdx.x;
    if (tid < NPB) { h[tid] = 0; cur[tid] = 0; }
    __syncthreads();
    for (int i = s + tid; i < e; i += 256) atomicAdd(&h[pairs[i] >> PSHIFT], 1);
    __syncthreads();
    if (tid < NPB) ex[tid] = h[tid];
    __syncthreads();
    for (int d = 1; d < NPB; d <<= 1) {
        int t = (tid < NPB && tid >= d) ? ex[tid - d] : 0;
        __syncthreads();
        if (tid < NPB) ex[tid] += t;
        __syncthreads();
    }
    if (tid < NPB) {
        int excl = ex[tid] - h[tid];     // inclusive -> exclusive
        ex[tid] = excl;
        int node = nb + tid;
        if (node < N) { cnt[node] = h[tid]; off[node] = s + excl; }
    }
    __syncthreads();
    for (int i = s + tid; i < e; i += 256) {
        uint p = pairs[i];
        int ld = p >> PSHIFT;
        int pos = atomicAdd(&cur[ld], 1);
        bucket[s + ex[ld] + pos] = (int)(p & ((1u << PSHIFT) - 1u));
    }
}

// ---------------- gather one row: (1+eps)*x[node] + sum x[src] ----------------
template<int BF16>
__device__ __forceinline__ float4 gather_row(
    const float* __restrict__ x, const ushort4* __restrict__ xr,
    const int* __restrict__ bucket, long long node, int lane,
    int start, int deg, float epsv)
{
    float4 acc = reinterpret_cast<const float4*>(x + node * D)[lane];
    acc.x *= epsv; acc.y *= epsv; acc.z *= epsv; acc.w *= epsv;
    int j = 0;
    if (BF16) {
        for (; j + 8 <= deg; j += 8) {
            int s[8];
            #pragma unroll
            for (int q = 0; q < 8; ++q) s[q] = bucket[start + j + q];
            ushort4 r[8];
            #pragma unroll
            for (int q = 0; q < 8; ++q) r[q] = xr[(long long)s[q] * 32 + lane];
            #pragma unroll
            for (int q = 0; q < 8; ++q) {
                acc.x += b2f(r[q].x); acc.y += b2f(r[q].y);
                acc.z += b2f(r[q].z); acc.w += b2f(r[q].w);
            }
        }
        for (; j < deg; ++j) {
            int s = bucket[start + j];
            ushort4 r = xr[(long long)s * 32 + lane];
            acc.x += b2f(r.x); acc.y += b2f(r.y); acc.z += b2f(r.z); acc.w += b2f(r.w);
        }
    } else {
        for (; j + 4 <= deg; j += 4) {
            int s0 = bucket[start + j + 0];
            int s1 = bucket[start + j + 1];
            int s2 = bucket[start + j + 2];
            int s3 = bucket[start + j + 3];
            float4 v0 = reinterpret_cast<const float4*>(x + (long long)s0 * D)[lane];
            float4 v1 = reinterpret_cast<const float4*>(x + (long long)s1 * D)[lane];
            float4 v2 = reinterpret_cast<const float4*>(x + (long long)s2 * D)[lane];
            float4 v3 = reinterpret_cast<const float4*>(x + (long long)s3 * D)[lane];
            acc.x += (v0.x + v1.x) + (v2.x + v3.x);
            acc.y += (v0.y + v1.y) + (v2.y + v3.y);
            acc.z += (v0.z + v1.z) + (v2.z + v3.z);
            acc.w += (v0.w + v1.w) + (v2.w + v3.w);
        }
        for (; j < deg; ++j) {
            int s = bucket[start + j];
            float4 v = reinterpret_cast<const float4*>(x + (long long)s * D)[lane];
            acc.x += v.x; acc.y += v.y; acc.z += v.z; acc.w += v.w;
        }
    }
    return acc;
}

// ---------------- split-mode gather: write Z (bf16) to workspace ----------------
__global__ __launch_bounds__(256, 8) void gin_gather(
    const float* __restrict__ x, const ushort* __restrict__ xb,
    const float* __restrict__ epsp,
    const int* __restrict__ off, const int* __restrict__ cnt,
    const int* __restrict__ bucket,
    ushort* __restrict__ zb, int N)
{
    const int tid  = threadIdx.x;
    const int lane = tid & 31;
    const int grp  = tid >> 5;
    const long long n0 = (long long)blockIdx.x * BMG;
    const float epsv = 1.0f + epsp[0];
    const ushort4* xr = (const ushort4*)xb;
    for (int rr = grp; rr < BMG; rr += 8) {
        long long node = n0 + rr;
        if (node >= N) break;
        int start = off[node];
        int deg   = cnt[node];
        float4 a = gather_row<1>(x, xr, bucket, node, lane, start, deg, epsv);
        ushort4 o;
        o.x = f2b(a.x); o.y = f2b(a.y); o.z = f2b(a.z); o.w = f2b(a.w);
        ((ushort4*)zb)[node * 32 + lane] = o;
    }
}

// ---------------- MFMA MLP over S (MT m-tiles of 16 rows), 4 waves ----------------
// mfma_f32_16x16x32_bf16 layouts: A row=l&15, k=(l>>4)*8+j (contiguous 8);
// B col=l&15, same k; C/D col=l&15, row=(l>>4)*4+reg (m89-verified).
template<int MT>
__device__ __forceinline__ void mlp_mfma(
    ushort* S, const ushort* __restrict__ w1t, const ushort* __restrict__ w2t,
    const float* __restrict__ b1, const float* __restrict__ b2,
    float* __restrict__ out, long long n0, int N, int tid)
{
    const int w   = tid >> 6;     // wave 0..3  -> n-tiles {2w, 2w+1}
    const int l   = tid & 63;
    const int c16 = l & 15;
    const int g   = l >> 4;
    const int n2a = 2 * w, n2b = 2 * w + 1;

    f32x4 acc[MT][2];
    {
        float bva = b1[n2a * 16 + c16];
        float bvb = b1[n2b * 16 + c16];
        #pragma unroll
        for (int m = 0; m < MT; ++m) {
            acc[m][0] = (f32x4){bva, bva, bva, bva};
            acc[m][1] = (f32x4){bvb, bvb, bvb, bvb};
        }
    }
    #pragma unroll
    for (int ks = 0; ks < 4; ++ks) {
        short8v a[MT];
        #pragma unroll
        for (int m = 0; m < MT; ++m)
            a[m] = *(const short8v*)&S[(m * 16 + c16) * LDH + ks * 32 + g * 8];
        short8v bA = *(const short8v*)&w1t[(n2a * 16 + c16) * D + ks * 32 + g * 8];
        short8v bB = *(const short8v*)&w1t[(n2b * 16 + c16) * D + ks * 32 + g * 8];
        #pragma unroll
        for (int m = 0; m < MT; ++m) {
            acc[m][0] = __builtin_amdgcn_mfma_f32_16x16x32_bf16(a[m], bA, acc[m][0], 0, 0, 0);
            acc[m][1] = __builtin_amdgcn_mfma_f32_16x16x32_bf16(a[m], bB, acc[m][1], 0, 0, 0);
        }
    }
    __syncthreads();   // all Z reads complete before H overwrite
    #pragma unroll
    for (int m = 0; m < MT; ++m) {
        #pragma unroll
        for (int ns = 0; ns < 2; ++ns) {
            int coln = (2 * w + ns) * 16 + c16;
            #pragma unroll
            for (int r = 0; r < 4; ++r) {
                float h = fmaxf(acc[m][ns][r], 0.f);
                S[(m * 16 + g * 4 + r) * LDH + coln] = f2b(h);
            }
        }
    }
    __syncthreads();
    {
        float bva = b2[n2a * 16 + c16];
        float bvb = b2[n2b * 16 + c16];
        #pragma unroll
        for (int m = 0; m < MT; ++m) {
            acc[m][0] = (f32x4){bva, bva, bva, bva};
            acc[m][1] = (f32x4){bvb, bvb, bvb, bvb};
        }
    }
    #pragma unroll
    for (int ks = 0; ks < 4; ++ks) {
        short8v a[MT];
        #pragma unroll
        for (int m = 0; m < MT; ++m)
            a[m] = *(const short8v*)&S[(m * 16 + c16) * LDH + ks * 32 + g * 8];
        short8v bA = *(const short8v*)&w2t[(n2a * 16 + c16) * D + ks * 32 + g * 8];
        short8v bB = *(const short8v*)&w2t[(n2b * 16 + c16) * D + ks * 32 + g * 8];
        #pragma unroll
        for (int m = 0; m < MT; ++m) {
            acc[m][0] = __builtin_amdgcn_mfma_f32_16x16x32_bf16(a[m], bA, acc[m][0], 0, 0, 0);
            acc[m][1] = __builtin_amdgcn_mfma_f32_16x16x32_bf16(a[m], bB, acc[m][1], 0, 0, 0);
        }
    }
    #pragma unroll
    for (int m = 0; m < MT; ++m) {
        #pragma unroll
        for (int ns = 0; ns < 2; ++ns) {
            long long coln = (2 * w + ns) * 16 + c16;
            #pragma unroll
            for (int r = 0; r < 4; ++r) {
                long long row = n0 + m * 16 + g * 4 + r;
                if (row < N) out[row * D + coln] = acc[m][ns][r];
            }
        }
    }
}

// ---------------- split-mode MLP: 64 rows/block ----------------
__global__ __launch_bounds__(256, 4) void gin_mlp(
    const ushort* __restrict__ zb, const ushort* __restrict__ w1t,
    const ushort* __restrict__ w2t, const float* __restrict__ b1,
    const float* __restrict__ b2, float* __restrict__ out, int N)
{
    __shared__ ushort S[64 * LDH];
    const int tid = threadIdx.x;
    const long long n0 = (long long)blockIdx.x * 64;
    for (int c = tid; c < 64 * 16; c += 256) {
        int row = c >> 4, cc = c & 15;
        uint4 v = ((const uint4*)(zb + (n0 + row) * D))[cc];
        *(uint4*)&S[row * LDH + cc * 8] = v;
    }
    __syncthreads();
    mlp_mfma<4>(S, w1t, w2t, b1, b2, out, n0, N, tid);
}

// ---------------- fused mode: gather -> LDS -> MFMA MLP ----------------
template<int BF16>
__global__ __launch_bounds__(256, 4) void gin_fused_mfma(
    const float* __restrict__ x, const ushort* __restrict__ xb,
    const float* __restrict__ epsp,
    const int* __restrict__ off, const int* __restrict__ cnt,
    const int* __restrict__ bucket,
    const ushort* __restrict__ w1t, const ushort* __restrict__ w2t,
    const float* __restrict__ b1, const float* __restrict__ b2,
    float* __restrict__ out, int N)
{
    __shared__ ushort S[BMG * LDH];
    const int tid  = threadIdx.x;
    const int lane = tid & 31;
    const int grp  = tid >> 5;
    const long long n0 = (long long)blockIdx.x * BMG;
    const float epsv = 1.0f + epsp[0];
    const ushort4* xr = (const ushort4*)xb;
    for (int rr = grp; rr < BMG; rr += 8) {
        long long node = n0 + rr;
        if (node >= N) break;
        int start = off[node];
        int deg   = cnt[node];
        float4 a = gather_row<BF16>(x, xr, bucket, node, lane, start, deg, epsv);
        ushort4 o;
        o.x = f2b(a.x); o.y = f2b(a.y); o.z = f2b(a.z); o.w = f2b(a.w);
        *(ushort4*)&S[rr * LDH + lane * 4] = o;
    }
    __syncthreads();
    mlp_mfma<2>(S, w1t, w2t, b1, b2, out, n0, N, tid);
}

extern "C" void kernel_launch(void* const* d_in, const int* in_sizes, int n_in,
                              void* d_out, int out_size, void* d_ws, size_t ws_size,
                              hipStream_t stream) {
    const float* x   = (const float*)d_in[0];
    const void*  ei  = d_in[1];
    const float* eps = (const float*)d_in[3];
    const float* W1  = (const float*)d_in[4];
    const float* b1  = (const float*)d_in[5];
    const float* W2  = (const float*)d_in[6];
    const float* b2  = (const float*)d_in[7];
    float* out = (float*)d_out;

    const int N = in_sizes[0] / D;   // 100000
    const int E = in_sizes[1] / 2;   // 1600000
    const int NC = (N + NPB - 1) / NPB;           // coarse buckets (1563)
    const int NCp = (NC + 1 + 255) & ~255;
    const long long Nr = ((long long)N + 63) & ~63LL;

    // ws: cnt[N] off[N] ccnt[NCp] ccur[NCp] coff[NCp] pairs[E] bucket[E] | xb | w1t w2t | zb
    int* cnt    = (int*)d_ws;
    int* off    = cnt + N;
    int* ccnt   = off + N;
    int* ccur   = ccnt + NCp;
    int* coff   = ccur + NCp;
    uint* pairs = (uint*)(coff + NCp);
    int* bucket = (int*)(pairs + E);
    size_t base   = ((size_t)2 * N + 3 * NCp + 2 * (size_t)E) * sizeof(int);
    size_t xb_off = (base + 15) & ~(size_t)15;
    size_t w1_off = xb_off + (size_t)N * D * sizeof(ushort);
    size_t w2_off = w1_off + (size_t)D * D * sizeof(ushort);
    size_t zb_off = w2_off + (size_t)D * D * sizeof(ushort);
    size_t need_fused = zb_off;
    size_t need_split = zb_off + (size_t)Nr * D * sizeof(ushort);
    size_t need_min   = xb_off + 2 * (size_t)D * D * sizeof(ushort);

    if (ws_size < need_min) return;   // cannot happen per prior rounds

    const bool has_bf16  = (ws_size >= need_fused);
    const bool has_split = (ws_size >= need_split);
    ushort *xb, *w1t, *w2t, *zb;
    if (has_bf16) {
        xb  = (ushort*)((char*)d_ws + xb_off);
        w1t = (ushort*)((char*)d_ws + w1_off);
        w2t = (ushort*)((char*)d_ws + w2_off);
        zb  = (ushort*)((char*)d_ws + zb_off);
    } else {
        xb  = nullptr;
        w1t = (ushort*)((char*)d_ws + xb_off);
        w2t = w1t + D * D;
        zb  = nullptr;
    }

    hipMemsetAsync(ccnt, 0, (size_t)2 * NCp * sizeof(int), stream);

    const int nhb = (E + 255) / 256;
    const int n4  = has_bf16 ? (N * D / 4) : 0;
    const int nxb = has_bf16 ? ((n4 + 255) / 256) : 0;
    gin_prep<<<nhb + nxb + 128, 256, 0, stream>>>(ei, ccnt, nhb, E,
                                                  (const float4*)x, (ushort4*)xb, n4, nxb,
                                                  W1, W2, w1t, w2t);
    gin_cscan<<<1, 1024, 0, stream>>>(ccnt, coff, NC);
    gin_cscatter<<<(E + 255) / 256, 256, 0, stream>>>(ei, coff, ccur, pairs, E);
    gin_fine<<<NC, 256, 0, stream>>>(pairs, coff, cnt, off, bucket, N);

    const int gblocks = (N + BMG - 1) / BMG;
    if (has_split) {
        gin_gather<<<gblocks, 256, 0, stream>>>(x, xb, eps, off, cnt, bucket, zb, N);
        gin_mlp<<<(int)((N + 63) / 64), 256, 0, stream>>>(zb, w1t, w2t, b1, b2, out, N);
    } else if (has_bf16) {
        gin_fused_mfma<1><<<gblocks, 256, 0, stream>>>(x, xb, eps, off, cnt, bucket,
                                                       w1t, w2t, b1, b2, out, N);
    } else {
        gin_fused_mfma<0><<<gblocks, 256, 0, stream>>>(x, xb, eps, off, cnt, bucket,
                                                       w1t, w2t, b1, b2, out, N);
    }
}

// Round 6
// 188.116 us; speedup vs baseline: 3.1928x; 3.1928x over previous
//
#include <hip/hip_runtime.h>

typedef unsigned int uint;
typedef unsigned short ushort;
typedef __attribute__((ext_vector_type(8))) short short8v;
typedef __attribute__((ext_vector_type(4))) float f32x4;

#define D 128
#define BMG 32       // gather tile rows
#define LDH 136      // LDS row stride in ushorts (272 B, b128-aligned, conflict-free)
#define NPB 64       // nodes per coarse bucket
#define PSHIFT 26    // pairs pack: local_dst(6b) << 26 | src(26b)  (needs N < 2^26)
#define NBLK 256     // histogram/scatter blocks (fixed partition)
#define MAXNC 2048   // max coarse buckets in LDS (N <= 131072)

// ---------- edge-index dtype hedge (int64 vs int32), wave-uniform ----------
__device__ __forceinline__ bool ei_is64(const int* ei32) {
    return ((ei32[1] | ei32[3] | ei32[5] | ei32[7]) == 0);
}
__device__ __forceinline__ float b2f(ushort u) { return __uint_as_float((uint)u << 16); }
__device__ __forceinline__ ushort f2b(float f) {   // RNE
    uint a = __float_as_uint(f);
    return (ushort)((a + 0x7fffu + ((a >> 16) & 1u)) >> 16);
}

// ---- prep: x -> bf16 + W1/W2 -> bf16 transpose (no atomics) ----
__global__ __launch_bounds__(256) void gin_prep(
    const float4* __restrict__ x4, ushort4* __restrict__ xb4, int n4, int nxb,
    const float* __restrict__ W1, const float* __restrict__ W2,
    ushort* __restrict__ w1t, ushort* __restrict__ w2t)
{
    int bid = blockIdx.x;
    if (bid < nxb) {
        int i = bid * 256 + threadIdx.x;
        if (i < n4) {
            float4 v = x4[i];
            ushort4 o;
            o.x = f2b(v.x); o.y = f2b(v.y); o.z = f2b(v.z); o.w = f2b(v.w);
            xb4[i] = o;
        }
    } else {
        int idx = (bid - nxb) * 256 + threadIdx.x;   // [0, 2*128*128)
        int which = idx >> 14;
        int rem   = idx & 16383;                     // n*128 + k
        int k = rem & 127, n = rem >> 7;
        const float* W = which ? W2 : W1;
        ushort* WT = which ? w2t : w1t;
        WT[rem] = f2b(W[k * D + n]);                 // WT[n][k] = W[k][n]
    }
}

// ---- per-block coarse histogram (LDS only, no global atomics) ----
__global__ __launch_bounds__(256) void gin_hist_pb(
    const void* __restrict__ ei_raw, int* __restrict__ harr, int NC, int E)
{
    __shared__ int h[MAXNC];
    for (int i = threadIdx.x; i < NC; i += 256) h[i] = 0;
    __syncthreads();
    const int* ei32 = (const int*)ei_raw;
    const long long* ei64 = (const long long*)ei_raw;
    const bool is64 = ei_is64(ei32);
    for (int e = blockIdx.x * 256 + threadIdx.x; e < E; e += 256 * NBLK) {
        int dst = is64 ? (int)ei64[e] : ei32[e];
        atomicAdd(&h[dst >> 6], 1);   // LDS atomic
    }
    __syncthreads();
    int* hb = harr + (size_t)blockIdx.x * NC;
    for (int i = threadIdx.x; i < NC; i += 256) hb[i] = h[i];
}

// ---- per-column scan across blocks: harr[b][c] -> exclusive prefix; tot[c] ----
__global__ __launch_bounds__(256) void gin_colsum(
    int* __restrict__ harr, int* __restrict__ tot, int NC)
{
    int c = blockIdx.x * 256 + threadIdx.x;
    if (c >= NC) return;
    int run = 0;
    for (int b = 0; b < NBLK; ++b) {
        int t = harr[(size_t)b * NC + c];
        harr[(size_t)b * NC + c] = run;
        run += t;
    }
    tot[c] = run;
}

// ---- exclusive scan of bucket totals (one block, up to 4096) ----
__global__ __launch_bounds__(1024) void gin_cscan(const int* __restrict__ ccnt,
                                                  int* __restrict__ coff, int nc) {
    __shared__ int ts[1024];
    int tid = threadIdx.x;
    int base = tid * 4;
    int v[4]; int s = 0;
    #pragma unroll
    for (int j = 0; j < 4; ++j) { int idx = base + j; v[j] = (idx < nc) ? ccnt[idx] : 0; s += v[j]; }
    ts[tid] = s;
    __syncthreads();
    for (int d = 1; d < 1024; d <<= 1) {
        int t = (tid >= d) ? ts[tid - d] : 0;
        __syncthreads();
        ts[tid] += t;
        __syncthreads();
    }
    int run = ts[tid] - s;
    #pragma unroll
    for (int j = 0; j < 4; ++j) { int idx = base + j; if (idx <= nc) coff[idx] = run; run += v[j]; }
}

// ---- coarse scatter: LDS-atomic positions, zero global atomics ----
__global__ __launch_bounds__(256) void gin_cscatter_pb(
    const void* __restrict__ ei_raw, const int* __restrict__ harr,
    const int* __restrict__ coff, uint* __restrict__ pairs, int NC, int E)
{
    __shared__ int cur[MAXNC];
    const int* hb = harr + (size_t)blockIdx.x * NC;
    for (int i = threadIdx.x; i < NC; i += 256) cur[i] = hb[i] + coff[i];
    __syncthreads();
    const int* ei32 = (const int*)ei_raw;
    const long long* ei64 = (const long long*)ei_raw;
    const bool is64 = ei_is64(ei32);
    for (int e = blockIdx.x * 256 + threadIdx.x; e < E; e += 256 * NBLK) {
        int dst, src;
        if (is64) { dst = (int)ei64[e]; src = (int)ei64[E + e]; }
        else      { dst = ei32[e];      src = ei32[E + e]; }
        int c = dst >> 6;
        int p = atomicAdd(&cur[c], 1);   // LDS atomic
        pairs[p] = ((uint)(dst & (NPB - 1)) << PSHIFT) | (uint)src;
    }
}

// ---- fine sort within each coarse bucket (one block per bucket) ----
__global__ __launch_bounds__(256) void gin_fine(
    const uint* __restrict__ pairs, const int* __restrict__ coff,
    int* __restrict__ cnt, int* __restrict__ off, int* __restrict__ bucket, int N)
{
    __shared__ int h[NPB], ex[NPB], cur[NPB];
    const int c = blockIdx.x;
    const int nb = c << 6;
    const int s = coff[c], e = coff[c + 1];
    const int tid = threadIdx.x;
    if (tid < NPB) { h[tid] = 0; cur[tid] = 0; }
    __syncthreads();
    for (int i = s + tid; i < e; i += 256) atomicAdd(&h[pairs[i] >> PSHIFT], 1);
    __syncthreads();
    if (tid < NPB) ex[tid] = h[tid];
    __syncthreads();
    for (int d = 1; d < NPB; d <<= 1) {
        int t = (tid < NPB && tid >= d) ? ex[tid - d] : 0;
        __syncthreads();
        if (tid < NPB) ex[tid] += t;
        __syncthreads();
    }
    if (tid < NPB) {
        int excl = ex[tid] - h[tid];
        ex[tid] = excl;
        int node = nb + tid;
        if (node < N) { cnt[node] = h[tid]; off[node] = s + excl; }
    }
    __syncthreads();
    for (int i = s + tid; i < e; i += 256) {
        uint p = pairs[i];
        int ld = p >> PSHIFT;
        int pos = atomicAdd(&cur[ld], 1);
        bucket[s + ex[ld] + pos] = (int)(p & ((1u << PSHIFT) - 1u));
    }
}

// ---------------- gather one row: (1+eps)*x[node] + sum x[src] ----------------
template<int BF16>
__device__ __forceinline__ float4 gather_row(
    const float* __restrict__ x, const ushort4* __restrict__ xr,
    const int* __restrict__ bucket, long long node, int lane,
    int start, int deg, float epsv)
{
    float4 acc;
    if (BF16) {
        ushort4 rs = xr[node * 32 + lane];
        acc.x = epsv * b2f(rs.x); acc.y = epsv * b2f(rs.y);
        acc.z = epsv * b2f(rs.z); acc.w = epsv * b2f(rs.w);
    } else {
        acc = reinterpret_cast<const float4*>(x + node * D)[lane];
        acc.x *= epsv; acc.y *= epsv; acc.z *= epsv; acc.w *= epsv;
    }
    int j = 0;
    if (BF16) {
        for (; j + 8 <= deg; j += 8) {
            int s[8];
            #pragma unroll
            for (int q = 0; q < 8; ++q) s[q] = bucket[start + j + q];
            ushort4 r[8];
            #pragma unroll
            for (int q = 0; q < 8; ++q) r[q] = xr[(long long)s[q] * 32 + lane];
            #pragma unroll
            for (int q = 0; q < 8; ++q) {
                acc.x += b2f(r[q].x); acc.y += b2f(r[q].y);
                acc.z += b2f(r[q].z); acc.w += b2f(r[q].w);
            }
        }
        for (; j < deg; ++j) {
            int s = bucket[start + j];
            ushort4 r = xr[(long long)s * 32 + lane];
            acc.x += b2f(r.x); acc.y += b2f(r.y); acc.z += b2f(r.z); acc.w += b2f(r.w);
        }
    } else {
        for (; j + 4 <= deg; j += 4) {
            int s0 = bucket[start + j + 0];
            int s1 = bucket[start + j + 1];
            int s2 = bucket[start + j + 2];
            int s3 = bucket[start + j + 3];
            float4 v0 = reinterpret_cast<const float4*>(x + (long long)s0 * D)[lane];
            float4 v1 = reinterpret_cast<const float4*>(x + (long long)s1 * D)[lane];
            float4 v2 = reinterpret_cast<const float4*>(x + (long long)s2 * D)[lane];
            float4 v3 = reinterpret_cast<const float4*>(x + (long long)s3 * D)[lane];
            acc.x += (v0.x + v1.x) + (v2.x + v3.x);
            acc.y += (v0.y + v1.y) + (v2.y + v3.y);
            acc.z += (v0.z + v1.z) + (v2.z + v3.z);
            acc.w += (v0.w + v1.w) + (v2.w + v3.w);
        }
        for (; j < deg; ++j) {
            int s = bucket[start + j];
            float4 v = reinterpret_cast<const float4*>(x + (long long)s * D)[lane];
            acc.x += v.x; acc.y += v.y; acc.z += v.z; acc.w += v.w;
        }
    }
    return acc;
}

// ---------------- split-mode gather: write Z (bf16) to workspace ----------------
__global__ __launch_bounds__(256, 8) void gin_gather(
    const float* __restrict__ x, const ushort* __restrict__ xb,
    const float* __restrict__ epsp,
    const int* __restrict__ off, const int* __restrict__ cnt,
    const int* __restrict__ bucket,
    ushort* __restrict__ zb, int N)
{
    const int tid  = threadIdx.x;
    const int lane = tid & 31;
    const int grp  = tid >> 5;
    const long long n0 = (long long)blockIdx.x * BMG;
    const float epsv = 1.0f + epsp[0];
    const ushort4* xr = (const ushort4*)xb;
    for (int rr = grp; rr < BMG; rr += 8) {
        long long node = n0 + rr;
        if (node >= N) break;
        int start = off[node];
        int deg   = cnt[node];
        float4 a = gather_row<1>(x, xr, bucket, node, lane, start, deg, epsv);
        ushort4 o;
        o.x = f2b(a.x); o.y = f2b(a.y); o.z = f2b(a.z); o.w = f2b(a.w);
        ((ushort4*)zb)[node * 32 + lane] = o;
    }
}

// ---------------- MFMA MLP over S (MT m-tiles of 16 rows), 4 waves ----------------
// mfma_f32_16x16x32_bf16 layouts: A row=l&15, k=(l>>4)*8+j (contiguous 8);
// B col=l&15, same k; C/D col=l&15, row=(l>>4)*4+reg (m89-verified).
template<int MT>
__device__ __forceinline__ void mlp_mfma(
    ushort* S, const ushort* __restrict__ w1t, const ushort* __restrict__ w2t,
    const float* __restrict__ b1, const float* __restrict__ b2,
    float* __restrict__ out, long long n0, int N, int tid)
{
    const int w   = tid >> 6;     // wave 0..3  -> n-tiles {2w, 2w+1}
    const int l   = tid & 63;
    const int c16 = l & 15;
    const int g   = l >> 4;
    const int n2a = 2 * w, n2b = 2 * w + 1;

    f32x4 acc[MT][2];
    {
        float bva = b1[n2a * 16 + c16];
        float bvb = b1[n2b * 16 + c16];
        #pragma unroll
        for (int m = 0; m < MT; ++m) {
            acc[m][0] = (f32x4){bva, bva, bva, bva};
            acc[m][1] = (f32x4){bvb, bvb, bvb, bvb};
        }
    }
    #pragma unroll
    for (int ks = 0; ks < 4; ++ks) {
        short8v a[MT];
        #pragma unroll
        for (int m = 0; m < MT; ++m)
            a[m] = *(const short8v*)&S[(m * 16 + c16) * LDH + ks * 32 + g * 8];
        short8v bA = *(const short8v*)&w1t[(n2a * 16 + c16) * D + ks * 32 + g * 8];
        short8v bB = *(const short8v*)&w1t[(n2b * 16 + c16) * D + ks * 32 + g * 8];
        #pragma unroll
        for (int m = 0; m < MT; ++m) {
            acc[m][0] = __builtin_amdgcn_mfma_f32_16x16x32_bf16(a[m], bA, acc[m][0], 0, 0, 0);
            acc[m][1] = __builtin_amdgcn_mfma_f32_16x16x32_bf16(a[m], bB, acc[m][1], 0, 0, 0);
        }
    }
    __syncthreads();   // all Z reads complete before H overwrite
    #pragma unroll
    for (int m = 0; m < MT; ++m) {
        #pragma unroll
        for (int ns = 0; ns < 2; ++ns) {
            int coln = (2 * w + ns) * 16 + c16;
            #pragma unroll
            for (int r = 0; r < 4; ++r) {
                float h = fmaxf(acc[m][ns][r], 0.f);
                S[(m * 16 + g * 4 + r) * LDH + coln] = f2b(h);
            }
        }
    }
    __syncthreads();
    {
        float bva = b2[n2a * 16 + c16];
        float bvb = b2[n2b * 16 + c16];
        #pragma unroll
        for (int m = 0; m < MT; ++m) {
            acc[m][0] = (f32x4){bva, bva, bva, bva};
            acc[m][1] = (f32x4){bvb, bvb, bvb, bvb};
        }
    }
    #pragma unroll
    for (int ks = 0; ks < 4; ++ks) {
        short8v a[MT];
        #pragma unroll
        for (int m = 0; m < MT; ++m)
            a[m] = *(const short8v*)&S[(m * 16 + c16) * LDH + ks * 32 + g * 8];
        short8v bA = *(const short8v*)&w2t[(n2a * 16 + c16) * D + ks * 32 + g * 8];
        short8v bB = *(const short8v*)&w2t[(n2b * 16 + c16) * D + ks * 32 + g * 8];
        #pragma unroll
        for (int m = 0; m < MT; ++m) {
            acc[m][0] = __builtin_amdgcn_mfma_f32_16x16x32_bf16(a[m], bA, acc[m][0], 0, 0, 0);
            acc[m][1] = __builtin_amdgcn_mfma_f32_16x16x32_bf16(a[m], bB, acc[m][1], 0, 0, 0);
        }
    }
    #pragma unroll
    for (int m = 0; m < MT; ++m) {
        #pragma unroll
        for (int ns = 0; ns < 2; ++ns) {
            long long coln = (2 * w + ns) * 16 + c16;
            #pragma unroll
            for (int r = 0; r < 4; ++r) {
                long long row = n0 + m * 16 + g * 4 + r;
                if (row < N) out[row * D + coln] = acc[m][ns][r];
            }
        }
    }
}

// ---------------- split-mode MLP: 64 rows/block ----------------
__global__ __launch_bounds__(256, 4) void gin_mlp(
    const ushort* __restrict__ zb, const ushort* __restrict__ w1t,
    const ushort* __restrict__ w2t, const float* __restrict__ b1,
    const float* __restrict__ b2, float* __restrict__ out, int N)
{
    __shared__ ushort S[64 * LDH];
    const int tid = threadIdx.x;
    const long long n0 = (long long)blockIdx.x * 64;
    for (int c = tid; c < 64 * 16; c += 256) {
        int row = c >> 4, cc = c & 15;
        uint4 v = ((const uint4*)(zb + (n0 + row) * D))[cc];
        *(uint4*)&S[row * LDH + cc * 8] = v;
    }
    __syncthreads();
    mlp_mfma<4>(S, w1t, w2t, b1, b2, out, n0, N, tid);
}

// ---------------- fused mode: gather -> LDS -> MFMA MLP ----------------
template<int BF16>
__global__ __launch_bounds__(256, 4) void gin_fused_mfma(
    const float* __restrict__ x, const ushort* __restrict__ xb,
    const float* __restrict__ epsp,
    const int* __restrict__ off, const int* __restrict__ cnt,
    const int* __restrict__ bucket,
    const ushort* __restrict__ w1t, const ushort* __restrict__ w2t,
    const float* __restrict__ b1, const float* __restrict__ b2,
    float* __restrict__ out, int N)
{
    __shared__ ushort S[BMG * LDH];
    const int tid  = threadIdx.x;
    const int lane = tid & 31;
    const int grp  = tid >> 5;
    const long long n0 = (long long)blockIdx.x * BMG;
    const float epsv = 1.0f + epsp[0];
    const ushort4* xr = (const ushort4*)xb;
    for (int rr = grp; rr < BMG; rr += 8) {
        long long node = n0 + rr;
        if (node >= N) break;
        int start = off[node];
        int deg   = cnt[node];
        float4 a = gather_row<BF16>(x, xr, bucket, node, lane, start, deg, epsv);
        ushort4 o;
        o.x = f2b(a.x); o.y = f2b(a.y); o.z = f2b(a.z); o.w = f2b(a.w);
        *(ushort4*)&S[rr * LDH + lane * 4] = o;
    }
    __syncthreads();
    mlp_mfma<2>(S, w1t, w2t, b1, b2, out, n0, N, tid);
}

extern "C" void kernel_launch(void* const* d_in, const int* in_sizes, int n_in,
                              void* d_out, int out_size, void* d_ws, size_t ws_size,
                              hipStream_t stream) {
    const float* x   = (const float*)d_in[0];
    const void*  ei  = d_in[1];
    const float* eps = (const float*)d_in[3];
    const float* W1  = (const float*)d_in[4];
    const float* b1  = (const float*)d_in[5];
    const float* W2  = (const float*)d_in[6];
    const float* b2  = (const float*)d_in[7];
    float* out = (float*)d_out;

    const int N = in_sizes[0] / D;   // 100000
    const int E = in_sizes[1] / 2;   // 1600000
    const int NC = (N + NPB - 1) / NPB;           // coarse buckets (1563; must be <= MAXNC)
    const int NCp = (NC + 1 + 255) & ~255;
    const long long Nr = ((long long)N + 63) & ~63LL;

    // ws: cnt[N] off[N] coff[NCp] tot[NCp] harr[NBLK*NC] pairs[E] bucket[E] | xb | w1t w2t | zb
    int* cnt    = (int*)d_ws;
    int* off    = cnt + N;
    int* coff   = off + N;
    int* tot    = coff + NCp;
    int* harr   = tot + NCp;
    uint* pairs = (uint*)(harr + (size_t)NBLK * NC);
    int* bucket = (int*)(pairs + E);
    size_t base   = ((size_t)2 * N + 2 * NCp + (size_t)NBLK * NC + 2 * (size_t)E) * sizeof(int);
    size_t xb_off = (base + 15) & ~(size_t)15;
    size_t w1_off = xb_off + (size_t)N * D * sizeof(ushort);
    size_t w2_off = w1_off + (size_t)D * D * sizeof(ushort);
    size_t zb_off = w2_off + (size_t)D * D * sizeof(ushort);
    size_t need_fused = zb_off;
    size_t need_split = zb_off + (size_t)Nr * D * sizeof(ushort);
    size_t need_min   = xb_off + 2 * (size_t)D * D * sizeof(ushort);

    if (ws_size < need_min || NC > MAXNC) return;   // cannot happen for this problem

    const bool has_bf16  = (ws_size >= need_fused);
    const bool has_split = (ws_size >= need_split);
    ushort *xb, *w1t, *w2t, *zb;
    if (has_bf16) {
        xb  = (ushort*)((char*)d_ws + xb_off);
        w1t = (ushort*)((char*)d_ws + w1_off);
        w2t = (ushort*)((char*)d_ws + w2_off);
        zb  = (ushort*)((char*)d_ws + zb_off);
    } else {
        xb  = nullptr;
        w1t = (ushort*)((char*)d_ws + xb_off);
        w2t = w1t + D * D;
        zb  = nullptr;
    }

    const int n4  = has_bf16 ? (N * D / 4) : 0;
    const int nxb = has_bf16 ? ((n4 + 255) / 256) : 0;
    gin_prep<<<nxb + 128, 256, 0, stream>>>((const float4*)x, (ushort4*)xb, n4, nxb,
                                            W1, W2, w1t, w2t);
    gin_hist_pb<<<NBLK, 256, 0, stream>>>(ei, harr, NC, E);
    gin_colsum<<<(NC + 255) / 256, 256, 0, stream>>>(harr, tot, NC);
    gin_cscan<<<1, 1024, 0, stream>>>(tot, coff, NC);
    gin_cscatter_pb<<<NBLK, 256, 0, stream>>>(ei, harr, coff, pairs, NC, E);
    gin_fine<<<NC, 256, 0, stream>>>(pairs, coff, cnt, off, bucket, N);

    const int gblocks = (N + BMG - 1) / BMG;
    if (has_split) {
        gin_gather<<<gblocks, 256, 0, stream>>>(x, xb, eps, off, cnt, bucket, zb, N);
        gin_mlp<<<(int)((N + 63) / 64), 256, 0, stream>>>(zb, w1t, w2t, b1, b2, out, N);
    } else if (has_bf16) {
        gin_fused_mfma<1><<<gblocks, 256, 0, stream>>>(x, xb, eps, off, cnt, bucket,
                                                       w1t, w2t, b1, b2, out, N);
    } else {
        gin_fused_mfma<0><<<gblocks, 256, 0, stream>>>(x, xb, eps, off, cnt, bucket,
                                                       w1t, w2t, b1, b2, out, N);
    }
}

// Round 7
// 170.599 us; speedup vs baseline: 3.5207x; 1.1027x over previous
//
#include <hip/hip_runtime.h>

typedef unsigned int uint;
typedef unsigned short ushort;
typedef __attribute__((ext_vector_type(8))) short short8v;
typedef __attribute__((ext_vector_type(4))) float f32x4;

#define D 128
#define LDH 136      // LDS row stride in ushorts (272 B, b128-aligned, conflict-free)
#define NPB 64       // nodes per coarse bucket
#define PSHIFT 26    // pairs pack: local_dst(6b) << 26 | src(26b)  (needs N < 2^26)
#define NBLK 256     // histogram/scatter blocks (fixed partition)
#define MAXNC 2048   // max coarse buckets in LDS (N <= 131072)
#define SRTCAP 4096  // per-bucket sorted-src LDS capacity (avg 1024, max ~1200)

// ---------- edge-index dtype hedge (int64 vs int32), wave-uniform ----------
__device__ __forceinline__ bool ei_is64(const int* ei32) {
    return ((ei32[1] | ei32[3] | ei32[5] | ei32[7]) == 0);
}
__device__ __forceinline__ float b2f(ushort u) { return __uint_as_float((uint)u << 16); }
__device__ __forceinline__ ushort f2b(float f) {   // RNE
    uint a = __float_as_uint(f);
    return (ushort)((a + 0x7fffu + ((a >> 16) & 1u)) >> 16);
}

// ---- prep: coarse histogram (LDS, per-block rows) + x->bf16 + W->bf16^T ----
__global__ __launch_bounds__(256) void gin_prep(
    const void* __restrict__ ei_raw, int* __restrict__ harr, int NC, int E,
    const float4* __restrict__ x4, ushort4* __restrict__ xb4, int n4, int nxb,
    const float* __restrict__ W1, const float* __restrict__ W2,
    ushort* __restrict__ w1t, ushort* __restrict__ w2t)
{
    __shared__ int h[MAXNC];
    int bid = blockIdx.x;
    if (bid < NBLK) {
        for (int i = threadIdx.x; i < NC; i += 256) h[i] = 0;
        __syncthreads();
        const int* ei32 = (const int*)ei_raw;
        const long long* ei64 = (const long long*)ei_raw;
        const bool is64 = ei_is64(ei32);
        for (int e = bid * 256 + threadIdx.x; e < E; e += 256 * NBLK) {
            int dst = is64 ? (int)ei64[e] : ei32[e];
            atomicAdd(&h[dst >> 6], 1);   // LDS atomic
        }
        __syncthreads();
        int* hb = harr + (size_t)bid * NC;
        for (int i = threadIdx.x; i < NC; i += 256) hb[i] = h[i];
    } else if (bid < NBLK + nxb) {
        int i = (bid - NBLK) * 256 + threadIdx.x;
        if (i < n4) {
            float4 v = x4[i];
            ushort4 o;
            o.x = f2b(v.x); o.y = f2b(v.y); o.z = f2b(v.z); o.w = f2b(v.w);
            xb4[i] = o;
        }
    } else {
        int idx = (bid - NBLK - nxb) * 256 + threadIdx.x;   // [0, 2*128*128)
        int which = idx >> 14;
        int rem   = idx & 16383;                            // n*128 + k
        int k = rem & 127, n = rem >> 7;
        const float* W = which ? W2 : W1;
        ushort* WT = which ? w2t : w1t;
        WT[rem] = f2b(W[k * D + n]);                        // WT[n][k] = W[k][n]
    }
}

// ---- per-column scan across blocks: harr[b][c] -> exclusive prefix; tot[c] ----
__global__ __launch_bounds__(256) void gin_colsum(
    int* __restrict__ harr, int* __restrict__ tot, int NC)
{
    int c = blockIdx.x * 256 + threadIdx.x;
    if (c >= NC) return;
    int run = 0;
    for (int b = 0; b < NBLK; ++b) {
        int t = harr[(size_t)b * NC + c];
        harr[(size_t)b * NC + c] = run;
        run += t;
    }
    tot[c] = run;
}

// ---- exclusive scan of bucket totals (one block, up to 4096) ----
__global__ __launch_bounds__(1024) void gin_cscan(const int* __restrict__ ccnt,
                                                  int* __restrict__ coff, int nc) {
    __shared__ int ts[1024];
    int tid = threadIdx.x;
    int base = tid * 4;
    int v[4]; int s = 0;
    #pragma unroll
    for (int j = 0; j < 4; ++j) { int idx = base + j; v[j] = (idx < nc) ? ccnt[idx] : 0; s += v[j]; }
    ts[tid] = s;
    __syncthreads();
    for (int d = 1; d < 1024; d <<= 1) {
        int t = (tid >= d) ? ts[tid - d] : 0;
        __syncthreads();
        ts[tid] += t;
        __syncthreads();
    }
    int run = ts[tid] - s;
    #pragma unroll
    for (int j = 0; j < 4; ++j) { int idx = base + j; if (idx <= nc) coff[idx] = run; run += v[j]; }
}

// ---- coarse scatter: LDS-atomic positions, zero global atomics ----
__global__ __launch_bounds__(256) void gin_cscatter_pb(
    const void* __restrict__ ei_raw, const int* __restrict__ harr,
    const int* __restrict__ coff, uint* __restrict__ pairs, int NC, int E)
{
    __shared__ int cur[MAXNC];
    const int* hb = harr + (size_t)blockIdx.x * NC;
    for (int i = threadIdx.x; i < NC; i += 256) cur[i] = hb[i] + coff[i];
    __syncthreads();
    const int* ei32 = (const int*)ei_raw;
    const long long* ei64 = (const long long*)ei_raw;
    const bool is64 = ei_is64(ei32);
    for (int e = blockIdx.x * 256 + threadIdx.x; e < E; e += 256 * NBLK) {
        int dst, src;
        if (is64) { dst = (int)ei64[e]; src = (int)ei64[E + e]; }
        else      { dst = ei32[e];      src = ei32[E + e]; }
        int c = dst >> 6;
        int p = atomicAdd(&cur[c], 1);   // LDS atomic
        pairs[p] = ((uint)(dst & (NPB - 1)) << PSHIFT) | (uint)src;
    }
}

// ---- fused fine-sort + gather: one block per coarse bucket ----
// Sorts the bucket's (ldst,src) pairs by node in LDS, then gathers
// Z[node] = (1+eps)*x[node] + sum x[src] and writes bf16 rows to zb.
__global__ __launch_bounds__(256, 8) void gin_sortgather(
    const uint* __restrict__ pairs, const int* __restrict__ coff,
    const ushort* __restrict__ xb, const float* __restrict__ epsp,
    ushort* __restrict__ zb, int N)
{
    __shared__ int srt[SRTCAP];
    __shared__ int hist[NPB], ex[NPB], cur[NPB];
    const int c = blockIdx.x;
    const int s = coff[c], e = coff[c + 1];
    const int size = e - s;
    const int tid = threadIdx.x;
    const float epsv = 1.0f + epsp[0];
    const long long nb = (long long)c << 6;
    const ushort4* xr = (const ushort4*)xb;
    const int lane = tid & 31, grp = tid >> 5;

    if (size <= SRTCAP) {
        if (tid < NPB) { hist[tid] = 0; cur[tid] = 0; }
        __syncthreads();
        for (int i = tid; i < size; i += 256) atomicAdd(&hist[pairs[s + i] >> PSHIFT], 1);
        __syncthreads();
        if (tid < NPB) ex[tid] = hist[tid];
        __syncthreads();
        for (int d = 1; d < NPB; d <<= 1) {
            int t = (tid < NPB && tid >= d) ? ex[tid - d] : 0;
            __syncthreads();
            if (tid < NPB) ex[tid] += t;
            __syncthreads();
        }
        if (tid < NPB) ex[tid] -= hist[tid];   // inclusive -> exclusive
        __syncthreads();
        for (int i = tid; i < size; i += 256) {
            uint p = pairs[s + i];
            int ld = p >> PSHIFT;
            int pos = atomicAdd(&cur[ld], 1);
            srt[ex[ld] + pos] = (int)(p & ((1u << PSHIFT) - 1u));
        }
        __syncthreads();
        for (int nn = grp; nn < NPB; nn += 8) {
            long long node = nb + nn;
            if (node >= N) break;
            int start = ex[nn];
            int deg   = hist[nn];
            ushort4 rs = xr[node * 32 + lane];
            float4 acc;
            acc.x = epsv * b2f(rs.x); acc.y = epsv * b2f(rs.y);
            acc.z = epsv * b2f(rs.z); acc.w = epsv * b2f(rs.w);
            int j = 0;
            for (; j + 8 <= deg; j += 8) {
                int sx[8];
                #pragma unroll
                for (int q = 0; q < 8; ++q) sx[q] = srt[start + j + q];
                ushort4 r[8];
                #pragma unroll
                for (int q = 0; q < 8; ++q) r[q] = xr[(long long)sx[q] * 32 + lane];
                #pragma unroll
                for (int q = 0; q < 8; ++q) {
                    acc.x += b2f(r[q].x); acc.y += b2f(r[q].y);
                    acc.z += b2f(r[q].z); acc.w += b2f(r[q].w);
                }
            }
            for (; j < deg; ++j) {
                int sx = srt[start + j];
                ushort4 r = xr[(long long)sx * 32 + lane];
                acc.x += b2f(r.x); acc.y += b2f(r.y); acc.z += b2f(r.z); acc.w += b2f(r.w);
            }
            ushort4 o;
            o.x = f2b(acc.x); o.y = f2b(acc.y); o.z = f2b(acc.z); o.w = f2b(acc.w);
            ((ushort4*)zb)[node * 32 + lane] = o;
        }
    } else {
        // oversized-bucket fallback (never triggers for avg-1024 buckets):
        // per node, scan the whole segment with uniform loads.
        for (int nn = grp; nn < NPB; nn += 8) {
            long long node = nb + nn;
            if (node >= N) break;
            ushort4 rs = xr[node * 32 + lane];
            float4 acc;
            acc.x = epsv * b2f(rs.x); acc.y = epsv * b2f(rs.y);
            acc.z = epsv * b2f(rs.z); acc.w = epsv * b2f(rs.w);
            for (int i = 0; i < size; ++i) {
                uint p = pairs[s + i];
                if ((int)(p >> PSHIFT) == nn) {
                    long long sx = p & ((1u << PSHIFT) - 1u);
                    ushort4 r = xr[sx * 32 + lane];
                    acc.x += b2f(r.x); acc.y += b2f(r.y);
                    acc.z += b2f(r.z); acc.w += b2f(r.w);
                }
            }
            ushort4 o;
            o.x = f2b(acc.x); o.y = f2b(acc.y); o.z = f2b(acc.z); o.w = f2b(acc.w);
            ((ushort4*)zb)[node * 32 + lane] = o;
        }
    }
}

// ---------------- MFMA MLP over S (MT m-tiles of 16 rows), 4 waves ----------------
// mfma_f32_16x16x32_bf16 layouts: A row=l&15, k=(l>>4)*8+j (contiguous 8);
// B col=l&15, same k; C/D col=l&15, row=(l>>4)*4+reg (m89-verified).
template<int MT>
__device__ __forceinline__ void mlp_mfma(
    ushort* S, const ushort* __restrict__ w1t, const ushort* __restrict__ w2t,
    const float* __restrict__ b1, const float* __restrict__ b2,
    float* __restrict__ out, long long n0, int N, int tid)
{
    const int w   = tid >> 6;     // wave 0..3  -> n-tiles {2w, 2w+1}
    const int l   = tid & 63;
    const int c16 = l & 15;
    const int g   = l >> 4;
    const int n2a = 2 * w, n2b = 2 * w + 1;

    f32x4 acc[MT][2];
    {
        float bva = b1[n2a * 16 + c16];
        float bvb = b1[n2b * 16 + c16];
        #pragma unroll
        for (int m = 0; m < MT; ++m) {
            acc[m][0] = (f32x4){bva, bva, bva, bva};
            acc[m][1] = (f32x4){bvb, bvb, bvb, bvb};
        }
    }
    #pragma unroll
    for (int ks = 0; ks < 4; ++ks) {
        short8v a[MT];
        #pragma unroll
        for (int m = 0; m < MT; ++m)
            a[m] = *(const short8v*)&S[(m * 16 + c16) * LDH + ks * 32 + g * 8];
        short8v bA = *(const short8v*)&w1t[(n2a * 16 + c16) * D + ks * 32 + g * 8];
        short8v bB = *(const short8v*)&w1t[(n2b * 16 + c16) * D + ks * 32 + g * 8];
        #pragma unroll
        for (int m = 0; m < MT; ++m) {
            acc[m][0] = __builtin_amdgcn_mfma_f32_16x16x32_bf16(a[m], bA, acc[m][0], 0, 0, 0);
            acc[m][1] = __builtin_amdgcn_mfma_f32_16x16x32_bf16(a[m], bB, acc[m][1], 0, 0, 0);
        }
    }
    __syncthreads();   // all Z reads complete before H overwrite
    #pragma unroll
    for (int m = 0; m < MT; ++m) {
        #pragma unroll
        for (int ns = 0; ns < 2; ++ns) {
            int coln = (2 * w + ns) * 16 + c16;
            #pragma unroll
            for (int r = 0; r < 4; ++r) {
                float h = fmaxf(acc[m][ns][r], 0.f);
                S[(m * 16 + g * 4 + r) * LDH + coln] = f2b(h);
            }
        }
    }
    __syncthreads();
    {
        float bva = b2[n2a * 16 + c16];
        float bvb = b2[n2b * 16 + c16];
        #pragma unroll
        for (int m = 0; m < MT; ++m) {
            acc[m][0] = (f32x4){bva, bva, bva, bva};
            acc[m][1] = (f32x4){bvb, bvb, bvb, bvb};
        }
    }
    #pragma unroll
    for (int ks = 0; ks < 4; ++ks) {
        short8v a[MT];
        #pragma unroll
        for (int m = 0; m < MT; ++m)
            a[m] = *(const short8v*)&S[(m * 16 + c16) * LDH + ks * 32 + g * 8];
        short8v bA = *(const short8v*)&w2t[(n2a * 16 + c16) * D + ks * 32 + g * 8];
        short8v bB = *(const short8v*)&w2t[(n2b * 16 + c16) * D + ks * 32 + g * 8];
        #pragma unroll
        for (int m = 0; m < MT; ++m) {
            acc[m][0] = __builtin_amdgcn_mfma_f32_16x16x32_bf16(a[m], bA, acc[m][0], 0, 0, 0);
            acc[m][1] = __builtin_amdgcn_mfma_f32_16x16x32_bf16(a[m], bB, acc[m][1], 0, 0, 0);
        }
    }
    #pragma unroll
    for (int m = 0; m < MT; ++m) {
        #pragma unroll
        for (int ns = 0; ns < 2; ++ns) {
            long long coln = (2 * w + ns) * 16 + c16;
            #pragma unroll
            for (int r = 0; r < 4; ++r) {
                long long row = n0 + m * 16 + g * 4 + r;
                if (row < N) out[row * D + coln] = acc[m][ns][r];
            }
        }
    }
}

// ---------------- MLP: 64 rows/block ----------------
__global__ __launch_bounds__(256, 4) void gin_mlp(
    const ushort* __restrict__ zb, const ushort* __restrict__ w1t,
    const ushort* __restrict__ w2t, const float* __restrict__ b1,
    const float* __restrict__ b2, float* __restrict__ out, int N)
{
    __shared__ ushort S[64 * LDH];
    const int tid = threadIdx.x;
    const long long n0 = (long long)blockIdx.x * 64;
    for (int c = tid; c < 64 * 16; c += 256) {
        int row = c >> 4, cc = c & 15;
        uint4 v = ((const uint4*)(zb + (n0 + row) * D))[cc];
        *(uint4*)&S[row * LDH + cc * 8] = v;
    }
    __syncthreads();
    mlp_mfma<4>(S, w1t, w2t, b1, b2, out, n0, N, tid);
}

extern "C" void kernel_launch(void* const* d_in, const int* in_sizes, int n_in,
                              void* d_out, int out_size, void* d_ws, size_t ws_size,
                              hipStream_t stream) {
    const float* x   = (const float*)d_in[0];
    const void*  ei  = d_in[1];
    const float* eps = (const float*)d_in[3];
    const float* W1  = (const float*)d_in[4];
    const float* b1  = (const float*)d_in[5];
    const float* W2  = (const float*)d_in[6];
    const float* b2  = (const float*)d_in[7];
    float* out = (float*)d_out;

    const int N = in_sizes[0] / D;   // 100000
    const int E = in_sizes[1] / 2;   // 1600000
    const int NC = (N + NPB - 1) / NPB;           // coarse buckets (1563 <= MAXNC)
    const int NCp = (NC + 1 + 255) & ~255;
    const long long Nr = ((long long)N + 63) & ~63LL;

    // ws: coff[NCp] tot[NCp] harr[NBLK*NC] pairs[E] | xb | w1t w2t | zb
    int* coff   = (int*)d_ws;
    int* tot    = coff + NCp;
    int* harr   = tot + NCp;
    uint* pairs = (uint*)(harr + (size_t)NBLK * NC);
    size_t base   = ((size_t)2 * NCp + (size_t)NBLK * NC + (size_t)E) * sizeof(int);
    size_t xb_off = (base + 15) & ~(size_t)15;
    size_t w1_off = xb_off + (size_t)N * D * sizeof(ushort);
    size_t w2_off = w1_off + (size_t)D * D * sizeof(ushort);
    size_t zb_off = w2_off + (size_t)D * D * sizeof(ushort);
    size_t need   = zb_off + (size_t)Nr * D * sizeof(ushort);

    if (ws_size < need || NC > MAXNC) return;   // cannot happen for this problem

    ushort* xb  = (ushort*)((char*)d_ws + xb_off);
    ushort* w1t = (ushort*)((char*)d_ws + w1_off);
    ushort* w2t = (ushort*)((char*)d_ws + w2_off);
    ushort* zb  = (ushort*)((char*)d_ws + zb_off);

    const int n4  = N * D / 4;
    const int nxb = (n4 + 255) / 256;
    gin_prep<<<NBLK + nxb + 128, 256, 0, stream>>>(ei, harr, NC, E,
                                                   (const float4*)x, (ushort4*)xb, n4, nxb,
                                                   W1, W2, w1t, w2t);
    gin_colsum<<<(NC + 255) / 256, 256, 0, stream>>>(harr, tot, NC);
    gin_cscan<<<1, 1024, 0, stream>>>(tot, coff, NC);
    gin_cscatter_pb<<<NBLK, 256, 0, stream>>>(ei, harr, coff, pairs, NC, E);
    gin_sortgather<<<NC, 256, 0, stream>>>(pairs, coff, xb, eps, zb, N);
    gin_mlp<<<(int)((N + 63) / 64), 256, 0, stream>>>(zb, w1t, w2t, b1, b2, out, N);
}

// Round 8
// 167.320 us; speedup vs baseline: 3.5897x; 1.0196x over previous
//
#include <hip/hip_runtime.h>

typedef unsigned int uint;
typedef unsigned short ushort;
typedef __attribute__((ext_vector_type(8))) short short8v;
typedef __attribute__((ext_vector_type(4))) float f32x4;

#define D 128
#define LDH 136      // LDS row stride in ushorts (272 B, b128-aligned, conflict-free)
#define NPB 32       // nodes per coarse bucket == MLP tile rows
#define PSHIFT 27    // pairs pack: local_dst(5b) << 27 | src(27b)  (needs N < 2^27)
#define NBLK 256     // histogram/scatter blocks (fixed partition)
#define MAXNC 4096   // max coarse buckets (N <= 131072)
#define SRTCAP 1024  // per-bucket sorted-src LDS capacity (avg 512, max ~650)

// ---------- edge-index dtype hedge (int64 vs int32), wave-uniform ----------
__device__ __forceinline__ bool ei_is64(const int* ei32) {
    return ((ei32[1] | ei32[3] | ei32[5] | ei32[7]) == 0);
}
__device__ __forceinline__ float b2f(ushort u) { return __uint_as_float((uint)u << 16); }
__device__ __forceinline__ ushort f2b(float f) {   // RNE
    uint a = __float_as_uint(f);
    return (ushort)((a + 0x7fffu + ((a >> 16) & 1u)) >> 16);
}

// ---- prep: coarse histogram (LDS, per-block rows) + x->bf16 + W->bf16^T ----
__global__ __launch_bounds__(256) void gin_prep(
    const void* __restrict__ ei_raw, int* __restrict__ harr, int NC, int E,
    const float4* __restrict__ x4, ushort4* __restrict__ xb4, int n4, int nxb,
    const float* __restrict__ W1, const float* __restrict__ W2,
    ushort* __restrict__ w1t, ushort* __restrict__ w2t)
{
    __shared__ int h[MAXNC];
    int bid = blockIdx.x;
    if (bid < NBLK) {
        for (int i = threadIdx.x; i < NC; i += 256) h[i] = 0;
        __syncthreads();
        const int* ei32 = (const int*)ei_raw;
        const long long* ei64 = (const long long*)ei_raw;
        const bool is64 = ei_is64(ei32);
        for (int e = bid * 256 + threadIdx.x; e < E; e += 256 * NBLK) {
            int dst = is64 ? (int)ei64[e] : ei32[e];
            atomicAdd(&h[dst / NPB], 1);   // LDS atomic
        }
        __syncthreads();
        int* hb = harr + (size_t)bid * NC;
        for (int i = threadIdx.x; i < NC; i += 256) hb[i] = h[i];
    } else if (bid < NBLK + nxb) {
        int i = (bid - NBLK) * 256 + threadIdx.x;
        if (i < n4) {
            float4 v = x4[i];
            ushort4 o;
            o.x = f2b(v.x); o.y = f2b(v.y); o.z = f2b(v.z); o.w = f2b(v.w);
            xb4[i] = o;
        }
    } else {
        int idx = (bid - NBLK - nxb) * 256 + threadIdx.x;   // [0, 2*128*128)
        int which = idx >> 14;
        int rem   = idx & 16383;                            // n*128 + k
        int k = rem & 127, n = rem >> 7;
        const float* W = which ? W2 : W1;
        ushort* WT = which ? w2t : w1t;
        WT[rem] = f2b(W[k * D + n]);                        // WT[n][k] = W[k][n]
    }
}

// ---- per-column scan across blocks: harr[b][c] -> exclusive prefix; tot[c] ----
__global__ __launch_bounds__(256) void gin_colsum(
    int* __restrict__ harr, int* __restrict__ tot, int NC)
{
    int c = blockIdx.x * 256 + threadIdx.x;
    if (c >= NC) return;
    int run = 0;
    for (int b = 0; b < NBLK; ++b) {
        int t = harr[(size_t)b * NC + c];
        harr[(size_t)b * NC + c] = run;
        run += t;
    }
    tot[c] = run;
}

// ---- coarse scatter with in-block scan of totals (no global atomics) ----
// Each block scans tot[] in LDS (identical work, all parallel); block 0 also
// publishes coff[0..NC] for the gather kernel.
__global__ __launch_bounds__(256) void gin_cscatter(
    const void* __restrict__ ei_raw, const int* __restrict__ harr,
    const int* __restrict__ tot, int* __restrict__ coff,
    uint* __restrict__ pairs, int NC, int E)
{
    __shared__ int sc[MAXNC + 1];
    __shared__ int part[256];
    const int tid = threadIdx.x;
    const int CH = (NC + 1 + 255) >> 8;
    const int base = tid * CH;
    // pass 1: local sums
    int lsum = 0;
    for (int j = 0; j < CH; ++j) {
        int idx = base + j;
        if (idx < NC) lsum += tot[idx];
    }
    part[tid] = lsum;
    __syncthreads();
    for (int d = 1; d < 256; d <<= 1) {
        int t = (tid >= d) ? part[tid - d] : 0;
        __syncthreads();
        part[tid] += t;
        __syncthreads();
    }
    int run = part[tid] - lsum;   // exclusive over chunks
    for (int j = 0; j < CH; ++j) {
        int idx = base + j;
        if (idx <= NC) { sc[idx] = run; if (idx < NC) run += tot[idx]; }
    }
    __syncthreads();
    if (blockIdx.x == 0)
        for (int i = tid; i <= NC; i += 256) coff[i] = sc[i];
    // build cur[] = coff + per-block offset, in place
    const int* hb = harr + (size_t)blockIdx.x * NC;
    for (int i = tid; i < NC; i += 256) sc[i] += hb[i];
    __syncthreads();
    const int* ei32 = (const int*)ei_raw;
    const long long* ei64 = (const long long*)ei_raw;
    const bool is64 = ei_is64(ei32);
    for (int e = blockIdx.x * 256 + tid; e < E; e += 256 * NBLK) {
        int dst, src;
        if (is64) { dst = (int)ei64[e]; src = (int)ei64[E + e]; }
        else      { dst = ei32[e];      src = ei32[E + e]; }
        int c = dst / NPB;
        int p = atomicAdd(&sc[c], 1);   // LDS atomic
        pairs[p] = ((uint)(dst & (NPB - 1)) << PSHIFT) | (uint)src;
    }
}

// ---------------- MFMA MLP over S (MT m-tiles of 16 rows), 4 waves ----------------
// mfma_f32_16x16x32_bf16 layouts: A row=l&15, k=(l>>4)*8+j (contiguous 8);
// B col=l&15, same k; C/D col=l&15, row=(l>>4)*4+reg (m89-verified).
template<int MT>
__device__ __forceinline__ void mlp_mfma(
    ushort* S, const ushort* __restrict__ w1t, const ushort* __restrict__ w2t,
    const float* __restrict__ b1, const float* __restrict__ b2,
    float* __restrict__ out, long long n0, int N, int tid)
{
    const int w   = tid >> 6;     // wave 0..3  -> n-tiles {2w, 2w+1}
    const int l   = tid & 63;
    const int c16 = l & 15;
    const int g   = l >> 4;
    const int n2a = 2 * w, n2b = 2 * w + 1;

    f32x4 acc[MT][2];
    {
        float bva = b1[n2a * 16 + c16];
        float bvb = b1[n2b * 16 + c16];
        #pragma unroll
        for (int m = 0; m < MT; ++m) {
            acc[m][0] = (f32x4){bva, bva, bva, bva};
            acc[m][1] = (f32x4){bvb, bvb, bvb, bvb};
        }
    }
    #pragma unroll
    for (int ks = 0; ks < 4; ++ks) {
        short8v a[MT];
        #pragma unroll
        for (int m = 0; m < MT; ++m)
            a[m] = *(const short8v*)&S[(m * 16 + c16) * LDH + ks * 32 + g * 8];
        short8v bA = *(const short8v*)&w1t[(n2a * 16 + c16) * D + ks * 32 + g * 8];
        short8v bB = *(const short8v*)&w1t[(n2b * 16 + c16) * D + ks * 32 + g * 8];
        #pragma unroll
        for (int m = 0; m < MT; ++m) {
            acc[m][0] = __builtin_amdgcn_mfma_f32_16x16x32_bf16(a[m], bA, acc[m][0], 0, 0, 0);
            acc[m][1] = __builtin_amdgcn_mfma_f32_16x16x32_bf16(a[m], bB, acc[m][1], 0, 0, 0);
        }
    }
    __syncthreads();   // all Z reads complete before H overwrite
    #pragma unroll
    for (int m = 0; m < MT; ++m) {
        #pragma unroll
        for (int ns = 0; ns < 2; ++ns) {
            int coln = (2 * w + ns) * 16 + c16;
            #pragma unroll
            for (int r = 0; r < 4; ++r) {
                float h = fmaxf(acc[m][ns][r], 0.f);
                S[(m * 16 + g * 4 + r) * LDH + coln] = f2b(h);
            }
        }
    }
    __syncthreads();
    {
        float bva = b2[n2a * 16 + c16];
        float bvb = b2[n2b * 16 + c16];
        #pragma unroll
        for (int m = 0; m < MT; ++m) {
            acc[m][0] = (f32x4){bva, bva, bva, bva};
            acc[m][1] = (f32x4){bvb, bvb, bvb, bvb};
        }
    }
    #pragma unroll
    for (int ks = 0; ks < 4; ++ks) {
        short8v a[MT];
        #pragma unroll
        for (int m = 0; m < MT; ++m)
            a[m] = *(const short8v*)&S[(m * 16 + c16) * LDH + ks * 32 + g * 8];
        short8v bA = *(const short8v*)&w2t[(n2a * 16 + c16) * D + ks * 32 + g * 8];
        short8v bB = *(const short8v*)&w2t[(n2b * 16 + c16) * D + ks * 32 + g * 8];
        #pragma unroll
        for (int m = 0; m < MT; ++m) {
            acc[m][0] = __builtin_amdgcn_mfma_f32_16x16x32_bf16(a[m], bA, acc[m][0], 0, 0, 0);
            acc[m][1] = __builtin_amdgcn_mfma_f32_16x16x32_bf16(a[m], bB, acc[m][1], 0, 0, 0);
        }
    }
    #pragma unroll
    for (int m = 0; m < MT; ++m) {
        #pragma unroll
        for (int ns = 0; ns < 2; ++ns) {
            long long coln = (2 * w + ns) * 16 + c16;
            #pragma unroll
            for (int r = 0; r < 4; ++r) {
                long long row = n0 + m * 16 + g * 4 + r;
                if (row < N) out[row * D + coln] = acc[m][ns][r];
            }
        }
    }
}

// ---- fused fine-sort + gather + MFMA MLP: one block per coarse bucket ----
__global__ __launch_bounds__(256, 8) void gin_sg_mlp(
    const uint* __restrict__ pairs, const int* __restrict__ coff,
    const ushort* __restrict__ xb, const float* __restrict__ epsp,
    const ushort* __restrict__ w1t, const ushort* __restrict__ w2t,
    const float* __restrict__ b1, const float* __restrict__ b2,
    float* __restrict__ out, int N)
{
    __shared__ int srt[SRTCAP];
    __shared__ ushort S[NPB * LDH];
    __shared__ int hist[NPB], ex[NPB], cur[NPB];
    const int c = blockIdx.x;
    const int s = coff[c], e = coff[c + 1];
    const int size = e - s;
    const int tid = threadIdx.x;
    const float epsv = 1.0f + epsp[0];
    const long long nb = (long long)c * NPB;
    const ushort4* xr = (const ushort4*)xb;
    const int lane = tid & 31, grp = tid >> 5;

    if (size <= SRTCAP) {
        if (tid < NPB) { hist[tid] = 0; cur[tid] = 0; }
        __syncthreads();
        for (int i = tid; i < size; i += 256) atomicAdd(&hist[pairs[s + i] >> PSHIFT], 1);
        __syncthreads();
        if (tid < NPB) ex[tid] = hist[tid];
        __syncthreads();
        for (int d = 1; d < NPB; d <<= 1) {
            int t = (tid < NPB && tid >= d) ? ex[tid - d] : 0;
            __syncthreads();
            if (tid < NPB) ex[tid] += t;
            __syncthreads();
        }
        if (tid < NPB) ex[tid] -= hist[tid];   // inclusive -> exclusive
        __syncthreads();
        for (int i = tid; i < size; i += 256) {
            uint p = pairs[s + i];
            int ld = p >> PSHIFT;
            int pos = atomicAdd(&cur[ld], 1);
            srt[ex[ld] + pos] = (int)(p & ((1u << PSHIFT) - 1u));
        }
        __syncthreads();
        for (int nn = grp; nn < NPB; nn += 8) {
            long long node = nb + nn;
            if (node >= N) break;
            int start = ex[nn];
            int deg   = hist[nn];
            ushort4 rs = xr[node * 32 + lane];
            float4 acc;
            acc.x = epsv * b2f(rs.x); acc.y = epsv * b2f(rs.y);
            acc.z = epsv * b2f(rs.z); acc.w = epsv * b2f(rs.w);
            int j = 0;
            for (; j + 8 <= deg; j += 8) {
                int sx[8];
                #pragma unroll
                for (int q = 0; q < 8; ++q) sx[q] = srt[start + j + q];
                ushort4 r[8];
                #pragma unroll
                for (int q = 0; q < 8; ++q) r[q] = xr[(long long)sx[q] * 32 + lane];
                #pragma unroll
                for (int q = 0; q < 8; ++q) {
                    acc.x += b2f(r[q].x); acc.y += b2f(r[q].y);
                    acc.z += b2f(r[q].z); acc.w += b2f(r[q].w);
                }
            }
            for (; j < deg; ++j) {
                int sx = srt[start + j];
                ushort4 r = xr[(long long)sx * 32 + lane];
                acc.x += b2f(r.x); acc.y += b2f(r.y); acc.z += b2f(r.z); acc.w += b2f(r.w);
            }
            ushort4 o;
            o.x = f2b(acc.x); o.y = f2b(acc.y); o.z = f2b(acc.z); o.w = f2b(acc.w);
            *(ushort4*)&S[nn * LDH + lane * 4] = o;
        }
    } else {
        // oversized-bucket fallback (statistically never): per-node scan.
        for (int nn = grp; nn < NPB; nn += 8) {
            long long node = nb + nn;
            if (node >= N) break;
            ushort4 rs = xr[node * 32 + lane];
            float4 acc;
            acc.x = epsv * b2f(rs.x); acc.y = epsv * b2f(rs.y);
            acc.z = epsv * b2f(rs.z); acc.w = epsv * b2f(rs.w);
            for (int i = 0; i < size; ++i) {
                uint p = pairs[s + i];
                if ((int)(p >> PSHIFT) == nn) {
                    long long sx = p & ((1u << PSHIFT) - 1u);
                    ushort4 r = xr[sx * 32 + lane];
                    acc.x += b2f(r.x); acc.y += b2f(r.y);
                    acc.z += b2f(r.z); acc.w += b2f(r.w);
                }
            }
            ushort4 o;
            o.x = f2b(acc.x); o.y = f2b(acc.y); o.z = f2b(acc.z); o.w = f2b(acc.w);
            *(ushort4*)&S[nn * LDH + lane * 4] = o;
        }
    }
    __syncthreads();
    mlp_mfma<2>(S, w1t, w2t, b1, b2, out, nb, N, tid);
}

extern "C" void kernel_launch(void* const* d_in, const int* in_sizes, int n_in,
                              void* d_out, int out_size, void* d_ws, size_t ws_size,
                              hipStream_t stream) {
    const float* x   = (const float*)d_in[0];
    const void*  ei  = d_in[1];
    const float* eps = (const float*)d_in[3];
    const float* W1  = (const float*)d_in[4];
    const float* b1  = (const float*)d_in[5];
    const float* W2  = (const float*)d_in[6];
    const float* b2  = (const float*)d_in[7];
    float* out = (float*)d_out;

    const int N = in_sizes[0] / D;   // 100000
    const int E = in_sizes[1] / 2;   // 1600000
    const int NC = (N + NPB - 1) / NPB;           // coarse buckets (3125 <= MAXNC)
    const int NCp = (NC + 1 + 255) & ~255;

    // ws: coff[NCp] tot[NCp] harr[NBLK*NC] pairs[E] | xb | w1t w2t
    int* coff   = (int*)d_ws;
    int* tot    = coff + NCp;
    int* harr   = tot + NCp;
    uint* pairs = (uint*)(harr + (size_t)NBLK * NC);
    size_t base   = ((size_t)2 * NCp + (size_t)NBLK * NC + (size_t)E) * sizeof(int);
    size_t xb_off = (base + 15) & ~(size_t)15;
    size_t w1_off = xb_off + (size_t)N * D * sizeof(ushort);
    size_t w2_off = w1_off + (size_t)D * D * sizeof(ushort);
    size_t need   = w2_off + (size_t)D * D * sizeof(ushort);

    if (ws_size < need || NC > MAXNC) return;   // cannot happen for this problem

    ushort* xb  = (ushort*)((char*)d_ws + xb_off);
    ushort* w1t = (ushort*)((char*)d_ws + w1_off);
    ushort* w2t = (ushort*)((char*)d_ws + w2_off);

    const int n4  = N * D / 4;
    const int nxb = (n4 + 255) / 256;
    gin_prep<<<NBLK + nxb + 128, 256, 0, stream>>>(ei, harr, NC, E,
                                                   (const float4*)x, (ushort4*)xb, n4, nxb,
                                                   W1, W2, w1t, w2t);
    gin_colsum<<<(NC + 255) / 256, 256, 0, stream>>>(harr, tot, NC);
    gin_cscatter<<<NBLK, 256, 0, stream>>>(ei, harr, tot, coff, pairs, NC, E);
    gin_sg_mlp<<<NC, 256, 0, stream>>>(pairs, coff, xb, eps, w1t, w2t, b1, b2, out, N);
}

// Round 9
// 155.994 us; speedup vs baseline: 3.8503x; 1.0726x over previous
//
#include <hip/hip_runtime.h>

typedef unsigned int uint;
typedef unsigned short ushort;
typedef __attribute__((ext_vector_type(8))) short short8v;
typedef __attribute__((ext_vector_type(4))) float f32x4;

#define D 128
#define LDH 136      // LDS row stride in ushorts (272 B, b128-aligned)
#define NPB 64       // nodes per coarse bucket == MLP tile rows (power of 2)
#define PSHIFT 26    // pairs pack: local_dst(6b) << 26 | src(26b)  (needs N < 2^26)
#define NBLK 256     // histogram/scatter blocks (fixed partition)
#define MAXNC 4096   // max coarse buckets (N <= 262144)
#define SRTCAP 4096  // per-bucket sorted-src capacity (avg 1024; 16 KB fits in S union)

// ---------- edge-index dtype hedge (int64 vs int32), wave-uniform ----------
__device__ __forceinline__ bool ei_is64(const int* ei32) {
    return ((ei32[1] | ei32[3] | ei32[5] | ei32[7]) == 0);
}
__device__ __forceinline__ float b2f(ushort u) { return __uint_as_float((uint)u << 16); }
__device__ __forceinline__ ushort f2b(float f) {   // RNE
    uint a = __float_as_uint(f);
    return (ushort)((a + 0x7fffu + ((a >> 16) & 1u)) >> 16);
}

// ---- prep: coarse histogram (LDS, per-block rows) + W->bf16^T ----
__global__ __launch_bounds__(256) void gin_prep(
    const void* __restrict__ ei_raw, int* __restrict__ harr, int NC, int E,
    const float* __restrict__ W1, const float* __restrict__ W2,
    ushort* __restrict__ w1t, ushort* __restrict__ w2t)
{
    __shared__ int h[MAXNC];
    int bid = blockIdx.x;
    if (bid < NBLK) {
        for (int i = threadIdx.x; i < NC; i += 256) h[i] = 0;
        __syncthreads();
        const int* ei32 = (const int*)ei_raw;
        const long long* ei64 = (const long long*)ei_raw;
        const bool is64 = ei_is64(ei32);
        for (int e = bid * 256 + threadIdx.x; e < E; e += 256 * NBLK) {
            int dst = is64 ? (int)ei64[e] : ei32[e];
            atomicAdd(&h[dst >> 6], 1);   // LDS atomic; NPB == 64
        }
        __syncthreads();
        int* hb = harr + (size_t)bid * NC;
        for (int i = threadIdx.x; i < NC; i += 256) hb[i] = h[i];
    } else {
        int idx = (bid - NBLK) * 256 + threadIdx.x;   // [0, 2*128*128)
        int which = idx >> 14;
        int rem   = idx & 16383;                      // n*128 + k
        int k = rem & 127, n = rem >> 7;
        const float* W = which ? W2 : W1;
        ushort* WT = which ? w2t : w1t;
        WT[rem] = f2b(W[k * D + n]);                  // WT[n][k] = W[k][n]
    }
}

// ---- per-column scan across blocks: harr[b][c] -> exclusive prefix; tot[c] ----
__global__ __launch_bounds__(256) void gin_colsum(
    int* __restrict__ harr, int* __restrict__ tot, int NC)
{
    int c = blockIdx.x * 256 + threadIdx.x;
    if (c >= NC) return;
    int run = 0;
    for (int b = 0; b < NBLK; ++b) {
        int t = harr[(size_t)b * NC + c];
        harr[(size_t)b * NC + c] = run;
        run += t;
    }
    tot[c] = run;
}

// ---- coarse scatter (blocks < NBLK) + x->bf16 convert (remaining blocks) ----
// Scatter blocks scan tot[] in LDS (identical, parallel); block 0 publishes coff.
__global__ __launch_bounds__(256) void gin_cscatter(
    const void* __restrict__ ei_raw, const int* __restrict__ harr,
    const int* __restrict__ tot, int* __restrict__ coff,
    uint* __restrict__ pairs, int NC, int E,
    const float4* __restrict__ x4, ushort4* __restrict__ xb4, int n4)
{
    __shared__ int sc[MAXNC + 1];
    __shared__ int part[256];
    const int tid = threadIdx.x;
    if (blockIdx.x >= NBLK) {            // x -> bf16 conversion blocks
        int i = (blockIdx.x - NBLK) * 256 + tid;
        if (i < n4) {
            float4 v = x4[i];
            ushort4 o;
            o.x = f2b(v.x); o.y = f2b(v.y); o.z = f2b(v.z); o.w = f2b(v.w);
            xb4[i] = o;
        }
        return;
    }
    const int CH = (NC + 1 + 255) >> 8;
    const int base = tid * CH;
    int lsum = 0;
    for (int j = 0; j < CH; ++j) {
        int idx = base + j;
        if (idx < NC) lsum += tot[idx];
    }
    part[tid] = lsum;
    __syncthreads();
    for (int d = 1; d < 256; d <<= 1) {
        int t = (tid >= d) ? part[tid - d] : 0;
        __syncthreads();
        part[tid] += t;
        __syncthreads();
    }
    int run = part[tid] - lsum;   // exclusive over chunks
    for (int j = 0; j < CH; ++j) {
        int idx = base + j;
        if (idx <= NC) { sc[idx] = run; if (idx < NC) run += tot[idx]; }
    }
    __syncthreads();
    if (blockIdx.x == 0)
        for (int i = tid; i <= NC; i += 256) coff[i] = sc[i];
    const int* hb = harr + (size_t)blockIdx.x * NC;
    for (int i = tid; i < NC; i += 256) sc[i] += hb[i];
    __syncthreads();
    const int* ei32 = (const int*)ei_raw;
    const long long* ei64 = (const long long*)ei_raw;
    const bool is64 = ei_is64(ei32);
    for (int e = blockIdx.x * 256 + tid; e < E; e += 256 * NBLK) {
        int dst, src;
        if (is64) { dst = (int)ei64[e]; src = (int)ei64[E + e]; }
        else      { dst = ei32[e];      src = ei32[E + e]; }
        int c = dst >> 6;
        int p = atomicAdd(&sc[c], 1);   // LDS atomic
        pairs[p] = ((uint)(dst & (NPB - 1)) << PSHIFT) | (uint)src;
    }
}

// ---------------- 8-wave MFMA MLP over S (64 rows), wave w -> n-tile w ----------------
// mfma_f32_16x16x32_bf16: A row=l&15, k=(l>>4)*8+j; B col=l&15; C/D col=l&15,
// row=(l>>4)*4+reg (m89-verified).
__device__ __forceinline__ void mlp8(
    ushort* S, const ushort* __restrict__ w1t, const ushort* __restrict__ w2t,
    const float* __restrict__ b1, const float* __restrict__ b2,
    float* __restrict__ out, long long n0, int N, int tid)
{
    const int w   = tid >> 6;     // wave 0..7 -> output cols [w*16, w*16+16)
    const int l   = tid & 63;
    const int c16 = l & 15;
    const int g   = l >> 4;

    f32x4 acc[4];
    {
        float bv = b1[w * 16 + c16];
        #pragma unroll
        for (int m = 0; m < 4; ++m) acc[m] = (f32x4){bv, bv, bv, bv};
    }
    #pragma unroll
    for (int ks = 0; ks < 4; ++ks) {
        short8v bB = *(const short8v*)&w1t[(w * 16 + c16) * D + ks * 32 + g * 8];
        #pragma unroll
        for (int m = 0; m < 4; ++m) {
            short8v a = *(const short8v*)&S[(m * 16 + c16) * LDH + ks * 32 + g * 8];
            acc[m] = __builtin_amdgcn_mfma_f32_16x16x32_bf16(a, bB, acc[m], 0, 0, 0);
        }
    }
    __syncthreads();   // all Z reads complete before H overwrite
    #pragma unroll
    for (int m = 0; m < 4; ++m)
        #pragma unroll
        for (int r = 0; r < 4; ++r)
            S[(m * 16 + g * 4 + r) * LDH + w * 16 + c16] = f2b(fmaxf(acc[m][r], 0.f));
    __syncthreads();
    {
        float bv = b2[w * 16 + c16];
        #pragma unroll
        for (int m = 0; m < 4; ++m) acc[m] = (f32x4){bv, bv, bv, bv};
    }
    #pragma unroll
    for (int ks = 0; ks < 4; ++ks) {
        short8v bB = *(const short8v*)&w2t[(w * 16 + c16) * D + ks * 32 + g * 8];
        #pragma unroll
        for (int m = 0; m < 4; ++m) {
            short8v a = *(const short8v*)&S[(m * 16 + c16) * LDH + ks * 32 + g * 8];
            acc[m] = __builtin_amdgcn_mfma_f32_16x16x32_bf16(a, bB, acc[m], 0, 0, 0);
        }
    }
    #pragma unroll
    for (int m = 0; m < 4; ++m)
        #pragma unroll
        for (int r = 0; r < 4; ++r) {
            long long row = n0 + m * 16 + g * 4 + r;
            if (row < N) out[row * D + w * 16 + c16] = acc[m][r];
        }
}

// ---- fused fine-sort + gather(regs) + MFMA MLP: one 512-thread block per bucket ----
// srt and S share one LDS union: srt used before the post-gather barrier,
// S written after it (gather accumulates in registers).
__global__ __launch_bounds__(512, 8) void gin_sg_mlp(
    const uint* __restrict__ pairs, const int* __restrict__ coff,
    const ushort* __restrict__ xb, const float* __restrict__ epsp,
    const ushort* __restrict__ w1t, const ushort* __restrict__ w2t,
    const float* __restrict__ b1, const float* __restrict__ b2,
    float* __restrict__ out, int N)
{
    __shared__ int4 U[(NPB * LDH * 2 + 15) / 16];   // 17408 B union
    int*    srt = (int*)U;                          // [SRTCAP] (16 KB)
    ushort* S   = (ushort*)U;                       // [NPB][LDH]
    __shared__ int hist[NPB], ex[NPB], cur[NPB];
    const int c = blockIdx.x;
    const int s = coff[c], e = coff[c + 1];
    const int size = e - s;
    const int tid = threadIdx.x;
    const float epsv = 1.0f + epsp[0];
    const long long nb = (long long)c * NPB;
    const ushort4* xr = (const ushort4*)xb;
    const int lane = tid & 31, grp = tid >> 5;   // 16 groups of 32 lanes

    if (size <= SRTCAP) {
        if (tid < NPB) { hist[tid] = 0; cur[tid] = 0; }
        __syncthreads();
        for (int i = tid; i < size; i += 512) atomicAdd(&hist[pairs[s + i] >> PSHIFT], 1);
        __syncthreads();
        if (tid < NPB) ex[tid] = hist[tid];
        __syncthreads();
        for (int d = 1; d < NPB; d <<= 1) {
            int t = (tid < NPB && tid >= d) ? ex[tid - d] : 0;
            __syncthreads();
            if (tid < NPB) ex[tid] += t;
            __syncthreads();
        }
        if (tid < NPB) ex[tid] -= hist[tid];   // inclusive -> exclusive
        __syncthreads();
        for (int i = tid; i < size; i += 512) {
            uint p = pairs[s + i];
            int ld = p >> PSHIFT;
            int pos = atomicAdd(&cur[ld], 1);
            srt[ex[ld] + pos] = (int)(p & ((1u << PSHIFT) - 1u));
        }
        __syncthreads();
        // gather to registers: each group owns 4 nodes {grp, grp+16, grp+32, grp+48}
        float4 accv[4];
        #pragma unroll
        for (int q = 0; q < 4; ++q) {
            int nn = grp + q * 16;
            long long node = nb + nn;
            float4 acc = make_float4(0.f, 0.f, 0.f, 0.f);
            if (node < N) {
                ushort4 rs = xr[node * 32 + lane];
                acc.x = epsv * b2f(rs.x); acc.y = epsv * b2f(rs.y);
                acc.z = epsv * b2f(rs.z); acc.w = epsv * b2f(rs.w);
                int start = ex[nn];
                int deg   = hist[nn];
                int j = 0;
                for (; j + 4 <= deg; j += 4) {
                    int s0 = srt[start + j + 0];
                    int s1 = srt[start + j + 1];
                    int s2 = srt[start + j + 2];
                    int s3 = srt[start + j + 3];
                    ushort4 r0 = xr[(long long)s0 * 32 + lane];
                    ushort4 r1 = xr[(long long)s1 * 32 + lane];
                    ushort4 r2 = xr[(long long)s2 * 32 + lane];
                    ushort4 r3 = xr[(long long)s3 * 32 + lane];
                    acc.x += (b2f(r0.x) + b2f(r1.x)) + (b2f(r2.x) + b2f(r3.x));
                    acc.y += (b2f(r0.y) + b2f(r1.y)) + (b2f(r2.y) + b2f(r3.y));
                    acc.z += (b2f(r0.z) + b2f(r1.z)) + (b2f(r2.z) + b2f(r3.z));
                    acc.w += (b2f(r0.w) + b2f(r1.w)) + (b2f(r2.w) + b2f(r3.w));
                }
                for (; j < deg; ++j) {
                    int sx = srt[start + j];
                    ushort4 r = xr[(long long)sx * 32 + lane];
                    acc.x += b2f(r.x); acc.y += b2f(r.y);
                    acc.z += b2f(r.z); acc.w += b2f(r.w);
                }
            }
            accv[q] = acc;
        }
        __syncthreads();   // all srt reads done; safe to overwrite with S
        #pragma unroll
        for (int q = 0; q < 4; ++q) {
            int nn = grp + q * 16;
            ushort4 o;
            o.x = f2b(accv[q].x); o.y = f2b(accv[q].y);
            o.z = f2b(accv[q].z); o.w = f2b(accv[q].w);
            *(ushort4*)&S[nn * LDH + lane * 4] = o;
        }
        __syncthreads();
    } else {
        // oversized-bucket fallback (statistically never): per-node global scan.
        #pragma unroll
        for (int q = 0; q < 4; ++q) {
            int nn = grp + q * 16;
            long long node = nb + nn;
            float4 acc = make_float4(0.f, 0.f, 0.f, 0.f);
            if (node < N) {
                ushort4 rs = xr[node * 32 + lane];
                acc.x = epsv * b2f(rs.x); acc.y = epsv * b2f(rs.y);
                acc.z = epsv * b2f(rs.z); acc.w = epsv * b2f(rs.w);
                for (int i = 0; i < size; ++i) {
                    uint p = pairs[s + i];
                    if ((int)(p >> PSHIFT) == nn) {
                        long long sx = p & ((1u << PSHIFT) - 1u);
                        ushort4 r = xr[sx * 32 + lane];
                        acc.x += b2f(r.x); acc.y += b2f(r.y);
                        acc.z += b2f(r.z); acc.w += b2f(r.w);
                    }
                }
            }
            ushort4 o;
            o.x = f2b(acc.x); o.y = f2b(acc.y); o.z = f2b(acc.z); o.w = f2b(acc.w);
            *(ushort4*)&S[nn * LDH + lane * 4] = o;
        }
        __syncthreads();
    }
    mlp8(S, w1t, w2t, b1, b2, out, nb, N, tid);
}

extern "C" void kernel_launch(void* const* d_in, const int* in_sizes, int n_in,
                              void* d_out, int out_size, void* d_ws, size_t ws_size,
                              hipStream_t stream) {
    const float* x   = (const float*)d_in[0];
    const void*  ei  = d_in[1];
    const float* eps = (const float*)d_in[3];
    const float* W1  = (const float*)d_in[4];
    const float* b1  = (const float*)d_in[5];
    const float* W2  = (const float*)d_in[6];
    const float* b2  = (const float*)d_in[7];
    float* out = (float*)d_out;

    const int N = in_sizes[0] / D;   // 100000
    const int E = in_sizes[1] / 2;   // 1600000
    const int NC = (N + NPB - 1) / NPB;           // coarse buckets (1563 <= MAXNC)
    const int NCp = (NC + 1 + 255) & ~255;

    // ws: coff[NCp] tot[NCp] harr[NBLK*NC] pairs[E] | xb | w1t w2t
    int* coff   = (int*)d_ws;
    int* tot    = coff + NCp;
    int* harr   = tot + NCp;
    uint* pairs = (uint*)(harr + (size_t)NBLK * NC);
    size_t base   = ((size_t)2 * NCp + (size_t)NBLK * NC + (size_t)E) * sizeof(int);
    size_t xb_off = (base + 15) & ~(size_t)15;
    size_t w1_off = xb_off + (size_t)N * D * sizeof(ushort);
    size_t w2_off = w1_off + (size_t)D * D * sizeof(ushort);
    size_t need   = w2_off + (size_t)D * D * sizeof(ushort);

    if (ws_size < need || NC > MAXNC) return;   // cannot happen for this problem

    ushort* xb  = (ushort*)((char*)d_ws + xb_off);
    ushort* w1t = (ushort*)((char*)d_ws + w1_off);
    ushort* w2t = (ushort*)((char*)d_ws + w2_off);

    const int n4  = N * D / 4;
    const int nxb = (n4 + 255) / 256;
    gin_prep<<<NBLK + 128, 256, 0, stream>>>(ei, harr, NC, E, W1, W2, w1t, w2t);
    gin_colsum<<<(NC + 255) / 256, 256, 0, stream>>>(harr, tot, NC);
    gin_cscatter<<<NBLK + nxb, 256, 0, stream>>>(ei, harr, tot, coff, pairs, NC, E,
                                                 (const float4*)x, (ushort4*)xb, n4);
    gin_sg_mlp<<<NC, 512, 0, stream>>>(pairs, coff, xb, eps, w1t, w2t, b1, b2, out, N);
}

// Round 10
// 126.311 us; speedup vs baseline: 4.7551x; 1.2350x over previous
//
#include <hip/hip_runtime.h>

typedef unsigned int uint;
typedef unsigned short ushort;
typedef __attribute__((ext_vector_type(8))) short short8v;
typedef __attribute__((ext_vector_type(4))) float f32x4;

#define D 128
#define LDH 136      // LDS row stride in ushorts (272 B, b128-aligned)
#define NPB 64       // nodes per coarse bucket == MLP tile rows (power of 2)
#define PSHIFT 26    // pairs pack: local_dst(6b) << 26 | src(26b)  (needs N < 2^26)
#define NBLK 256     // histogram/scatter blocks (fixed partition)
#define MAXNC 4096   // max coarse buckets (N <= 262144)
#define SRTCAP 4096  // per-bucket sorted-src capacity (avg 1024; 16 KB fits in S union)

// ---------- edge-index dtype hedge (int64 vs int32), wave-uniform ----------
__device__ __forceinline__ bool ei_is64(const int* ei32) {
    return ((ei32[1] | ei32[3] | ei32[5] | ei32[7]) == 0);
}
__device__ __forceinline__ float b2f(ushort u) { return __uint_as_float((uint)u << 16); }
__device__ __forceinline__ ushort f2b(float f) {   // RNE
    uint a = __float_as_uint(f);
    return (ushort)((a + 0x7fffu + ((a >> 16) & 1u)) >> 16);
}

// ---- prep: coarse histogram -> TRANSPOSED harr[c][b]  +  W->bf16^T ----
__global__ __launch_bounds__(256) void gin_prep(
    const void* __restrict__ ei_raw, int* __restrict__ harr, int NC, int E,
    const float* __restrict__ W1, const float* __restrict__ W2,
    ushort* __restrict__ w1t, ushort* __restrict__ w2t)
{
    __shared__ int h[MAXNC];
    int bid = blockIdx.x;
    if (bid < NBLK) {
        for (int i = threadIdx.x; i < NC; i += 256) h[i] = 0;
        __syncthreads();
        const int* ei32 = (const int*)ei_raw;
        const long long* ei64 = (const long long*)ei_raw;
        const bool is64 = ei_is64(ei32);
        for (int e = bid * 256 + threadIdx.x; e < E; e += 256 * NBLK) {
            int dst = is64 ? (int)ei64[e] : ei32[e];
            atomicAdd(&h[dst >> 6], 1);   // LDS atomic; NPB == 64
        }
        __syncthreads();
        for (int i = threadIdx.x; i < NC; i += 256)
            harr[(size_t)i * NBLK + bid] = h[i];          // transposed write
    } else {
        int idx = (bid - NBLK) * 256 + threadIdx.x;   // [0, 2*128*128)
        int which = idx >> 14;
        int rem   = idx & 16383;                      // n*128 + k
        int k = rem & 127, n = rem >> 7;
        const float* W = which ? W2 : W1;
        ushort* WT = which ? w2t : w1t;
        WT[rem] = f2b(W[k * D + n]);                  // WT[n][k] = W[k][n]
    }
}

// ---- column scan, one wave per column: harr[c][0..255] -> exclusive; tot[c] ----
__global__ __launch_bounds__(512) void gin_colsum(
    int* __restrict__ harr, int* __restrict__ tot, int NC)
{
    int wv   = (blockIdx.x * 512 + threadIdx.x) >> 6;   // global wave id = column
    int lane = threadIdx.x & 63;
    if (wv >= NC) return;
    int4* col = (int4*)(harr + (size_t)wv * NBLK);
    int4 v = col[lane];                       // coalesced 16 B/lane
    int s = v.x + v.y + v.z + v.w;
    int inc = s;
    #pragma unroll
    for (int d = 1; d < 64; d <<= 1) {
        int t = __shfl_up(inc, d, 64);
        if (lane >= d) inc += t;
    }
    int excl = inc - s;
    int4 o;
    o.x = excl; o.y = excl + v.x; o.z = o.y + v.y; o.w = o.z + v.z;
    col[lane] = o;
    if (lane == 63) tot[wv] = inc;
}

// ---- coarse scatter (blocks < NBLK) + x->bf16 convert (remaining blocks) ----
// Scatter blocks scan tot[] in LDS (identical, parallel); block 0 publishes coff.
__global__ __launch_bounds__(256) void gin_cscatter(
    const void* __restrict__ ei_raw, const int* __restrict__ harr,
    const int* __restrict__ tot, int* __restrict__ coff,
    uint* __restrict__ pairs, int NC, int E,
    const float4* __restrict__ x4, ushort4* __restrict__ xb4, int n4)
{
    __shared__ int sc[MAXNC + 1];
    __shared__ int part[256];
    const int tid = threadIdx.x;
    if (blockIdx.x >= NBLK) {            // x -> bf16 conversion blocks
        int i = (blockIdx.x - NBLK) * 256 + tid;
        if (i < n4) {
            float4 v = x4[i];
            ushort4 o;
            o.x = f2b(v.x); o.y = f2b(v.y); o.z = f2b(v.z); o.w = f2b(v.w);
            xb4[i] = o;
        }
        return;
    }
    const int CH = (NC + 1 + 255) >> 8;
    const int base = tid * CH;
    int lsum = 0;
    for (int j = 0; j < CH; ++j) {
        int idx = base + j;
        if (idx < NC) lsum += tot[idx];
    }
    part[tid] = lsum;
    __syncthreads();
    for (int d = 1; d < 256; d <<= 1) {
        int t = (tid >= d) ? part[tid - d] : 0;
        __syncthreads();
        part[tid] += t;
        __syncthreads();
    }
    int run = part[tid] - lsum;   // exclusive over chunks
    for (int j = 0; j < CH; ++j) {
        int idx = base + j;
        if (idx <= NC) { sc[idx] = run; if (idx < NC) run += tot[idx]; }
    }
    __syncthreads();
    if (blockIdx.x == 0)
        for (int i = tid; i <= NC; i += 256) coff[i] = sc[i];
    for (int i = tid; i < NC; i += 256)
        sc[i] += harr[(size_t)i * NBLK + blockIdx.x];     // transposed read
    __syncthreads();
    const int* ei32 = (const int*)ei_raw;
    const long long* ei64 = (const long long*)ei_raw;
    const bool is64 = ei_is64(ei32);
    for (int e = blockIdx.x * 256 + tid; e < E; e += 256 * NBLK) {
        int dst, src;
        if (is64) { dst = (int)ei64[e]; src = (int)ei64[E + e]; }
        else      { dst = ei32[e];      src = ei32[E + e]; }
        int c = dst >> 6;
        int p = atomicAdd(&sc[c], 1);   // LDS atomic
        pairs[p] = ((uint)(dst & (NPB - 1)) << PSHIFT) | (uint)src;
    }
}

// ---------------- 8-wave MFMA MLP over S (64 rows), wave w -> n-tile w ----------------
// mfma_f32_16x16x32_bf16: A row=l&15, k=(l>>4)*8+j; B col=l&15; C/D col=l&15,
// row=(l>>4)*4+reg (m89-verified).
__device__ __forceinline__ void mlp8(
    ushort* S, const ushort* __restrict__ w1t, const ushort* __restrict__ w2t,
    const float* __restrict__ b1, const float* __restrict__ b2,
    float* __restrict__ out, long long n0, int N, int tid)
{
    const int w   = tid >> 6;     // wave 0..7 -> output cols [w*16, w*16+16)
    const int l   = tid & 63;
    const int c16 = l & 15;
    const int g   = l >> 4;

    f32x4 acc[4];
    {
        float bv = b1[w * 16 + c16];
        #pragma unroll
        for (int m = 0; m < 4; ++m) acc[m] = (f32x4){bv, bv, bv, bv};
    }
    #pragma unroll
    for (int ks = 0; ks < 4; ++ks) {
        short8v bB = *(const short8v*)&w1t[(w * 16 + c16) * D + ks * 32 + g * 8];
        #pragma unroll
        for (int m = 0; m < 4; ++m) {
            short8v a = *(const short8v*)&S[(m * 16 + c16) * LDH + ks * 32 + g * 8];
            acc[m] = __builtin_amdgcn_mfma_f32_16x16x32_bf16(a, bB, acc[m], 0, 0, 0);
        }
    }
    __syncthreads();   // all Z reads complete before H overwrite
    #pragma unroll
    for (int m = 0; m < 4; ++m)
        #pragma unroll
        for (int r = 0; r < 4; ++r)
            S[(m * 16 + g * 4 + r) * LDH + w * 16 + c16] = f2b(fmaxf(acc[m][r], 0.f));
    __syncthreads();
    {
        float bv = b2[w * 16 + c16];
        #pragma unroll
        for (int m = 0; m < 4; ++m) acc[m] = (f32x4){bv, bv, bv, bv};
    }
    #pragma unroll
    for (int ks = 0; ks < 4; ++ks) {
        short8v bB = *(const short8v*)&w2t[(w * 16 + c16) * D + ks * 32 + g * 8];
        #pragma unroll
        for (int m = 0; m < 4; ++m) {
            short8v a = *(const short8v*)&S[(m * 16 + c16) * LDH + ks * 32 + g * 8];
            acc[m] = __builtin_amdgcn_mfma_f32_16x16x32_bf16(a, bB, acc[m], 0, 0, 0);
        }
    }
    #pragma unroll
    for (int m = 0; m < 4; ++m)
        #pragma unroll
        for (int r = 0; r < 4; ++r) {
            long long row = n0 + m * 16 + g * 4 + r;
            if (row < N) out[row * D + w * 16 + c16] = acc[m][r];
        }
}

// ---- fused fine-sort + gather(regs) + MFMA MLP: one 512-thread block per bucket ----
// pairs staged in registers (1 global read); wave-0 shuffle scan (2 barriers);
// srt and S share one LDS union.
__global__ __launch_bounds__(512, 8) void gin_sg_mlp(
    const uint* __restrict__ pairs, const int* __restrict__ coff,
    const ushort* __restrict__ xb, const float* __restrict__ epsp,
    const ushort* __restrict__ w1t, const ushort* __restrict__ w2t,
    const float* __restrict__ b1, const float* __restrict__ b2,
    float* __restrict__ out, int N)
{
    __shared__ int4 U[(NPB * LDH * 2 + 15) / 16];   // 17408 B union
    int*    srt = (int*)U;                          // [SRTCAP] (16 KB)
    ushort* S   = (ushort*)U;                       // [NPB][LDH]
    __shared__ int hist[NPB], ex[NPB], cur[NPB];
    const int c = blockIdx.x;
    const int s = coff[c], e = coff[c + 1];
    const int size = e - s;
    const int tid = threadIdx.x;
    const float epsv = 1.0f + epsp[0];
    const long long nb = (long long)c * NPB;
    const ushort4* xr = (const ushort4*)xb;
    const int lane = tid & 31, grp = tid >> 5;   // 16 groups of 32 lanes

    if (size <= SRTCAP) {
        if (tid < NPB) { hist[tid] = 0; cur[tid] = 0; }
        uint pr[8]; int np = 0;
        #pragma unroll
        for (int k = 0; k < 8; ++k) {
            int i = tid + k * 512;
            if (i < size) { pr[k] = pairs[s + i]; np = k + 1; }
        }
        __syncthreads();
        #pragma unroll
        for (int k = 0; k < 8; ++k)
            if (k < np) atomicAdd(&hist[pr[k] >> PSHIFT], 1);
        __syncthreads();
        if (tid < 64) {                     // single-wave shuffle scan
            int v = hist[tid];
            int inc = v;
            #pragma unroll
            for (int d = 1; d < 64; d <<= 1) {
                int t = __shfl_up(inc, d, 64);
                if (tid >= d) inc += t;
            }
            ex[tid] = inc - v;              // exclusive
        }
        __syncthreads();
        #pragma unroll
        for (int k = 0; k < 8; ++k)
            if (k < np) {
                uint p = pr[k];
                int ld = p >> PSHIFT;
                int pos = atomicAdd(&cur[ld], 1);
                srt[ex[ld] + pos] = (int)(p & ((1u << PSHIFT) - 1u));
            }
        __syncthreads();
        // gather to registers: each group owns 4 nodes {grp, grp+16, grp+32, grp+48}
        float4 accv[4];
        #pragma unroll
        for (int q = 0; q < 4; ++q) {
            int nn = grp + q * 16;
            long long node = nb + nn;
            float4 acc = make_float4(0.f, 0.f, 0.f, 0.f);
            if (node < N) {
                ushort4 rs = xr[node * 32 + lane];
                acc.x = epsv * b2f(rs.x); acc.y = epsv * b2f(rs.y);
                acc.z = epsv * b2f(rs.z); acc.w = epsv * b2f(rs.w);
                int start = ex[nn];
                int deg   = hist[nn];
                int j = 0;
                for (; j + 8 <= deg; j += 8) {
                    int sx[8];
                    #pragma unroll
                    for (int u = 0; u < 8; ++u) sx[u] = srt[start + j + u];
                    ushort4 r[8];
                    #pragma unroll
                    for (int u = 0; u < 8; ++u) r[u] = xr[(long long)sx[u] * 32 + lane];
                    #pragma unroll
                    for (int u = 0; u < 8; ++u) {
                        acc.x += b2f(r[u].x); acc.y += b2f(r[u].y);
                        acc.z += b2f(r[u].z); acc.w += b2f(r[u].w);
                    }
                }
                for (; j < deg; ++j) {
                    int sx = srt[start + j];
                    ushort4 r = xr[(long long)sx * 32 + lane];
                    acc.x += b2f(r.x); acc.y += b2f(r.y);
                    acc.z += b2f(r.z); acc.w += b2f(r.w);
                }
            }
            accv[q] = acc;
        }
        __syncthreads();   // all srt reads done; safe to overwrite with S
        #pragma unroll
        for (int q = 0; q < 4; ++q) {
            int nn = grp + q * 16;
            ushort4 o;
            o.x = f2b(accv[q].x); o.y = f2b(accv[q].y);
            o.z = f2b(accv[q].z); o.w = f2b(accv[q].w);
            *(ushort4*)&S[nn * LDH + lane * 4] = o;
        }
        __syncthreads();
    } else {
        // oversized-bucket fallback (statistically never): per-node global scan.
        #pragma unroll
        for (int q = 0; q < 4; ++q) {
            int nn = grp + q * 16;
            long long node = nb + nn;
            float4 acc = make_float4(0.f, 0.f, 0.f, 0.f);
            if (node < N) {
                ushort4 rs = xr[node * 32 + lane];
                acc.x = epsv * b2f(rs.x); acc.y = epsv * b2f(rs.y);
                acc.z = epsv * b2f(rs.z); acc.w = epsv * b2f(rs.w);
                for (int i = 0; i < size; ++i) {
                    uint p = pairs[s + i];
                    if ((int)(p >> PSHIFT) == nn) {
                        long long sx = p & ((1u << PSHIFT) - 1u);
                        ushort4 r = xr[sx * 32 + lane];
                        acc.x += b2f(r.x); acc.y += b2f(r.y);
                        acc.z += b2f(r.z); acc.w += b2f(r.w);
                    }
                }
            }
            ushort4 o;
            o.x = f2b(acc.x); o.y = f2b(acc.y); o.z = f2b(acc.z); o.w = f2b(acc.w);
            *(ushort4*)&S[nn * LDH + lane * 4] = o;
        }
        __syncthreads();
    }
    mlp8(S, w1t, w2t, b1, b2, out, nb, N, tid);
}

extern "C" void kernel_launch(void* const* d_in, const int* in_sizes, int n_in,
                              void* d_out, int out_size, void* d_ws, size_t ws_size,
                              hipStream_t stream) {
    const float* x   = (const float*)d_in[0];
    const void*  ei  = d_in[1];
    const float* eps = (const float*)d_in[3];
    const float* W1  = (const float*)d_in[4];
    const float* b1  = (const float*)d_in[5];
    const float* W2  = (const float*)d_in[6];
    const float* b2  = (const float*)d_in[7];
    float* out = (float*)d_out;

    const int N = in_sizes[0] / D;   // 100000
    const int E = in_sizes[1] / 2;   // 1600000
    const int NC = (N + NPB - 1) / NPB;           // coarse buckets (1563 <= MAXNC)
    const int NCp = (NC + 1 + 255) & ~255;

    // ws: coff[NCp] tot[NCp] harr[NC*NBLK] pairs[E] | xb | w1t w2t
    int* coff   = (int*)d_ws;
    int* tot    = coff + NCp;
    int* harr   = tot + NCp;
    uint* pairs = (uint*)(harr + (size_t)NBLK * NC);
    size_t base   = ((size_t)2 * NCp + (size_t)NBLK * NC + (size_t)E) * sizeof(int);
    size_t xb_off = (base + 15) & ~(size_t)15;
    size_t w1_off = xb_off + (size_t)N * D * sizeof(ushort);
    size_t w2_off = w1_off + (size_t)D * D * sizeof(ushort);
    size_t need   = w2_off + (size_t)D * D * sizeof(ushort);

    if (ws_size < need || NC > MAXNC) return;   // cannot happen for this problem

    ushort* xb  = (ushort*)((char*)d_ws + xb_off);
    ushort* w1t = (ushort*)((char*)d_ws + w1_off);
    ushort* w2t = (ushort*)((char*)d_ws + w2_off);

    const int n4  = N * D / 4;
    const int nxb = (n4 + 255) / 256;
    gin_prep<<<NBLK + 128, 256, 0, stream>>>(ei, harr, NC, E, W1, W2, w1t, w2t);
    gin_colsum<<<(NC * 64 + 511) / 512, 512, 0, stream>>>(harr, tot, NC);
    gin_cscatter<<<NBLK + nxb, 256, 0, stream>>>(ei, harr, tot, coff, pairs, NC, E,
                                                 (const float4*)x, (ushort4*)xb, n4);
    gin_sg_mlp<<<NC, 512, 0, stream>>>(pairs, coff, xb, eps, w1t, w2t, b1, b2, out, N);
}